// Round 1
// baseline (1046.698 us; speedup 1.0000x reference)
//
#include <hip/hip_runtime.h>

#define DD 64      // embedding dim
#define LL 200     // history length
#define GG 6       // genres
#define LAMBDA 0.001f

__device__ __forceinline__ float wave_reduce_sum(float v) {
    #pragma unroll
    for (int off = 32; off > 0; off >>= 1)
        v += __shfl_xor(v, off, 64);
    return v;
}

__global__ __launch_bounds__(256)
void dual_tower_kernel(
    const int* __restrict__ user_id,      // [B]
    const int* __restrict__ history,      // [B,L]
    const int* __restrict__ top_genres,   // [B,G]
    const int* __restrict__ item_id,      // [B]
    const int* __restrict__ tmdb_genres,  // [B,G]
    const float* __restrict__ ts_diff,    // [B,L]
    const float* __restrict__ u_avg,      // [B]
    const float* __restrict__ activity,   // [B]
    const float* __restrict__ rel_year,   // [B]
    const float* __restrict__ i_avg,      // [B]
    const float* __restrict__ revenue,    // [B]
    const float* __restrict__ emb_item,   // [V_ITEM, D]
    const float* __restrict__ emb_genre,  // [V_GENRE, D]
    const float* __restrict__ emb_user,   // [V_USER, D]
    const float* __restrict__ ut_cont_w,  // [D,2]
    const float* __restrict__ ut_cont_b,  // [D]
    const float* __restrict__ ut_w1,      // [128,256]
    const float* __restrict__ ut_b1,      // [128]
    const float* __restrict__ ut_g,       // [128]
    const float* __restrict__ ut_be,      // [128]
    const float* __restrict__ ut_w2,      // [64,128]
    const float* __restrict__ ut_b2,      // [64]
    const float* __restrict__ it_cont_w,  // [D,3]
    const float* __restrict__ it_cont_b,  // [D]
    const float* __restrict__ it_w1,      // [128,192]
    const float* __restrict__ it_b1,      // [128]
    const float* __restrict__ it_g,       // [128]
    const float* __restrict__ it_be,      // [128]
    const float* __restrict__ it_w2,      // [64,128]
    const float* __restrict__ it_b2,      // [64]
    float* __restrict__ out,              // [2*B*64] (u_out then i_out)
    int B)
{
    const int wave = threadIdx.x >> 6;
    const int lane = threadIdx.x & 63;
    const int b = blockIdx.x * 4 + wave;   // grid = B/4 exactly (B % 4 == 0)

    __shared__ float s_x[4][256];
    __shared__ float s_h[4][128];
    float* xw = s_x[wave];
    float* hw = s_h[wave];

    //================= user tower features =================
    const float u_e = emb_user[(long)user_id[b] * DD + lane];

    // history pooling: sum_l exp(-lam*ts)*mask * emb_item[h_l][d] / (sum w)
    const int*   hrow = history + (long)b * LL;
    const float* trow = ts_diff + (long)b * LL;
    float acc = 0.f, wsum = 0.f;
    #pragma unroll 4
    for (int l = 0; l < LL; ++l) {
        const int idx = hrow[l];
        const float w = (idx > 0) ? __expf(-LAMBDA * trow[l]) : 0.f;
        acc  = fmaf(w, emb_item[(long)idx * DD + lane], acc);
        wsum += w;
    }
    const float hist_pool = acc / (wsum + 1e-8f);

    // genre pooling (user)
    const int* grow = top_genres + (long)b * GG;
    float gacc = 0.f, gw = 0.f;
    #pragma unroll
    for (int g = 0; g < GG; ++g) {
        const int idx = grow[g];
        const float m = (idx > 0) ? 1.f : 0.f;
        gacc = fmaf(m, emb_genre[idx * DD + lane], gacc);
        gw  += m;
    }
    const float ug_pool = gacc / (gw + 1e-8f);

    // continuous features (user)
    const float ua = u_avg[b], av = activity[b];
    float ucont = fmaf(ua, ut_cont_w[lane * 2 + 0],
                  fmaf(av, ut_cont_w[lane * 2 + 1], ut_cont_b[lane]));
    ucont = fmaxf(ucont, 0.f);

    xw[lane]       = u_e;
    xw[64 + lane]  = hist_pool;
    xw[128 + lane] = ug_pool;
    xw[192 + lane] = ucont;
    __syncthreads();

    //================= user MLP =================
    // layer 1: [256] -> [128], 2 outputs per lane
    float y0 = ut_b1[lane];
    float y1 = ut_b1[lane + 64];
    {
        const float4* wr0 = (const float4*)(ut_w1 + (long)lane * 256);
        const float4* wr1 = (const float4*)(ut_w1 + (long)(lane + 64) * 256);
        const float4* xv  = (const float4*)xw;
        #pragma unroll 8
        for (int k = 0; k < 64; ++k) {
            const float4 x4 = xv[k];
            const float4 a  = wr0[k];
            const float4 c  = wr1[k];
            y0 = fmaf(x4.x, a.x, fmaf(x4.y, a.y, fmaf(x4.z, a.z, fmaf(x4.w, a.w, y0))));
            y1 = fmaf(x4.x, c.x, fmaf(x4.y, c.y, fmaf(x4.z, c.z, fmaf(x4.w, c.w, y1))));
        }
    }
    // layernorm over 128 (two-pass: mean, then var of deviations)
    {
        const float mean = wave_reduce_sum(y0 + y1) * (1.f / 128.f);
        const float d0 = y0 - mean, d1 = y1 - mean;
        const float var = wave_reduce_sum(d0 * d0 + d1 * d1) * (1.f / 128.f);
        const float rstd = rsqrtf(var + 1e-5f);
        const float h0 = fmaxf(fmaf(d0 * rstd, ut_g[lane],      ut_be[lane]),      0.f);
        const float h1 = fmaxf(fmaf(d1 * rstd, ut_g[lane + 64], ut_be[lane + 64]), 0.f);
        hw[lane]      = h0;
        hw[lane + 64] = h1;
    }
    __syncthreads();
    // layer 2: [128] -> [64], 1 output per lane, then l2norm
    {
        float o = ut_b2[lane];
        const float4* wr = (const float4*)(ut_w2 + (long)lane * 128);
        const float4* hv = (const float4*)hw;
        #pragma unroll 8
        for (int k = 0; k < 32; ++k) {
            const float4 h4 = hv[k];
            const float4 a  = wr[k];
            o = fmaf(h4.x, a.x, fmaf(h4.y, a.y, fmaf(h4.z, a.z, fmaf(h4.w, a.w, o))));
        }
        const float nrm = sqrtf(wave_reduce_sum(o * o));
        out[(long)b * DD + lane] = o / fmaxf(nrm, 1e-12f);
    }
    __syncthreads();

    //================= item tower features =================
    const float i_e = emb_item[(long)item_id[b] * DD + lane];

    const int* igrow = tmdb_genres + (long)b * GG;
    float iacc = 0.f, iw = 0.f;
    #pragma unroll
    for (int g = 0; g < GG; ++g) {
        const int idx = igrow[g];
        const float m = (idx > 0) ? 1.f : 0.f;
        iacc = fmaf(m, emb_genre[idx * DD + lane], iacc);
        iw  += m;
    }
    const float ig_pool = iacc / (iw + 1e-8f);

    const float ry = rel_year[b], ir = i_avg[b], rv = revenue[b];
    float icont = fmaf(ry, it_cont_w[lane * 3 + 0],
                  fmaf(ir, it_cont_w[lane * 3 + 1],
                  fmaf(rv, it_cont_w[lane * 3 + 2], it_cont_b[lane])));
    icont = fmaxf(icont, 0.f);

    xw[lane]       = i_e;
    xw[64 + lane]  = ig_pool;
    xw[128 + lane] = icont;
    __syncthreads();

    //================= item MLP =================
    float z0 = it_b1[lane];
    float z1 = it_b1[lane + 64];
    {
        const float4* wr0 = (const float4*)(it_w1 + (long)lane * 192);
        const float4* wr1 = (const float4*)(it_w1 + (long)(lane + 64) * 192);
        const float4* xv  = (const float4*)xw;
        #pragma unroll 8
        for (int k = 0; k < 48; ++k) {
            const float4 x4 = xv[k];
            const float4 a  = wr0[k];
            const float4 c  = wr1[k];
            z0 = fmaf(x4.x, a.x, fmaf(x4.y, a.y, fmaf(x4.z, a.z, fmaf(x4.w, a.w, z0))));
            z1 = fmaf(x4.x, c.x, fmaf(x4.y, c.y, fmaf(x4.z, c.z, fmaf(x4.w, c.w, z1))));
        }
    }
    {
        const float mean = wave_reduce_sum(z0 + z1) * (1.f / 128.f);
        const float d0 = z0 - mean, d1 = z1 - mean;
        const float var = wave_reduce_sum(d0 * d0 + d1 * d1) * (1.f / 128.f);
        const float rstd = rsqrtf(var + 1e-5f);
        const float h0 = fmaxf(fmaf(d0 * rstd, it_g[lane],      it_be[lane]),      0.f);
        const float h1 = fmaxf(fmaf(d1 * rstd, it_g[lane + 64], it_be[lane + 64]), 0.f);
        hw[lane]      = h0;
        hw[lane + 64] = h1;
    }
    __syncthreads();
    {
        float o = it_b2[lane];
        const float4* wr = (const float4*)(it_w2 + (long)lane * 128);
        const float4* hv = (const float4*)hw;
        #pragma unroll 8
        for (int k = 0; k < 32; ++k) {
            const float4 h4 = hv[k];
            const float4 a  = wr[k];
            o = fmaf(h4.x, a.x, fmaf(h4.y, a.y, fmaf(h4.z, a.z, fmaf(h4.w, a.w, o))));
        }
        const float nrm = sqrtf(wave_reduce_sum(o * o));
        out[(long)B * DD + (long)b * DD + lane] = o / fmaxf(nrm, 1e-12f);
    }
}

extern "C" void kernel_launch(void* const* d_in, const int* in_sizes, int n_in,
                              void* d_out, int out_size, void* d_ws, size_t ws_size,
                              hipStream_t stream) {
    const int*   user_id     = (const int*)  d_in[0];
    const int*   history     = (const int*)  d_in[1];
    const int*   top_genres  = (const int*)  d_in[2];
    const int*   item_id     = (const int*)  d_in[3];
    const int*   tmdb_genres = (const int*)  d_in[4];
    const float* ts_diff     = (const float*)d_in[5];
    const float* u_avg       = (const float*)d_in[6];
    const float* activity    = (const float*)d_in[7];
    const float* rel_year    = (const float*)d_in[8];
    const float* i_avg       = (const float*)d_in[9];
    const float* revenue     = (const float*)d_in[10];
    const float* emb_item    = (const float*)d_in[11];
    const float* emb_genre   = (const float*)d_in[12];
    const float* emb_user    = (const float*)d_in[13];
    const float* ut_cont_w   = (const float*)d_in[14];
    const float* ut_cont_b   = (const float*)d_in[15];
    const float* ut_w1       = (const float*)d_in[16];
    const float* ut_b1       = (const float*)d_in[17];
    const float* ut_g        = (const float*)d_in[18];
    const float* ut_be       = (const float*)d_in[19];
    const float* ut_w2       = (const float*)d_in[20];
    const float* ut_b2       = (const float*)d_in[21];
    const float* it_cont_w   = (const float*)d_in[22];
    const float* it_cont_b   = (const float*)d_in[23];
    const float* it_w1       = (const float*)d_in[24];
    const float* it_b1       = (const float*)d_in[25];
    const float* it_g        = (const float*)d_in[26];
    const float* it_be       = (const float*)d_in[27];
    const float* it_w2       = (const float*)d_in[28];
    const float* it_b2       = (const float*)d_in[29];

    const int B = in_sizes[0];   // 16384, divisible by 4
    dim3 grid(B / 4), block(256);
    hipLaunchKernelGGL(dual_tower_kernel, grid, block, 0, stream,
        user_id, history, top_genres, item_id, tmdb_genres,
        ts_diff, u_avg, activity, rel_year, i_avg, revenue,
        emb_item, emb_genre, emb_user,
        ut_cont_w, ut_cont_b, ut_w1, ut_b1, ut_g, ut_be, ut_w2, ut_b2,
        it_cont_w, it_cont_b, it_w1, it_b1, it_g, it_be, it_w2, it_b2,
        (float*)d_out, B);
}

// Round 2
// 261.211 us; speedup vs baseline: 4.0071x; 4.0071x over previous
//
#include <hip/hip_runtime.h>

#define DD 64      // embedding dim
#define LL 200     // history length
#define GG 6       // genres
#define LAMBDA 0.001f
#define R   16     // rows per block (kernel 2)
#define RPW 4      // rows per wave  (kernel 2)

__device__ __forceinline__ float wave_reduce_sum(float v) {
    #pragma unroll
    for (int off = 32; off > 0; off >>= 1)
        v += __shfl_xor(v, off, 64);
    return v;
}

//======================================================================
// Kernel 1: history pooling only. One wave per row, 4 waves/block.
//======================================================================
__global__ __launch_bounds__(256)
void hist_pool_kernel(const int* __restrict__ history,
                      const float* __restrict__ ts_diff,
                      const float* __restrict__ emb_item,
                      float* __restrict__ hist_out,   // [B,64]
                      int B)
{
    const int wave = threadIdx.x >> 6;
    const int lane = threadIdx.x & 63;
    const int b = blockIdx.x * 4 + wave;

    __shared__ float2 s_p[4][LL];   // (w, idx-bits)

    const int*   hrow = history + (size_t)b * LL;
    const float* trow = ts_diff + (size_t)b * LL;

    // lane-parallel precompute of weights & indices (coalesced reads)
    float wpart = 0.f;
    for (int l = lane; l < LL; l += 64) {
        const int idx = hrow[l];
        const float w = (idx > 0) ? __expf(-LAMBDA * trow[l]) : 0.f;
        s_p[wave][l] = make_float2(w, __int_as_float(idx));
        wpart += w;
    }
    const float wsum = wave_reduce_sum(wpart);
    __syncthreads();

    // 8-deep unrolled gather: 8 independent loads in flight
    float acc = 0.f;
    #pragma unroll 1
    for (int l0 = 0; l0 < LL; l0 += 8) {
        float e[8], w[8];
        #pragma unroll
        for (int i = 0; i < 8; ++i) {
            const float2 p = s_p[wave][l0 + i];
            w[i] = p.x;
            e[i] = emb_item[(size_t)__float_as_int(p.y) * DD + lane];
        }
        #pragma unroll
        for (int i = 0; i < 8; ++i) acc = fmaf(w[i], e[i], acc);
    }
    hist_out[(size_t)b * DD + lane] = acc / (wsum + 1e-8f);
}

//======================================================================
// Kernel 2: feature build + both tower MLPs, weights staged in LDS.
// 256 threads, 16 rows/block (4 rows per wave).
//======================================================================
__global__ __launch_bounds__(256)
void mlp_kernel(
    const int* __restrict__ user_id, const int* __restrict__ top_genres,
    const int* __restrict__ item_id, const int* __restrict__ tmdb_genres,
    const float* __restrict__ hist_pool,   // [B,64] (from kernel 1)
    const float* __restrict__ u_avg, const float* __restrict__ activity,
    const float* __restrict__ rel_year, const float* __restrict__ i_avg,
    const float* __restrict__ revenue,
    const float* __restrict__ emb_item, const float* __restrict__ emb_genre,
    const float* __restrict__ emb_user,
    const float* __restrict__ ut_cont_w, const float* __restrict__ ut_cont_b,
    const float* __restrict__ ut_w1, const float* __restrict__ ut_b1,
    const float* __restrict__ ut_g,  const float* __restrict__ ut_be,
    const float* __restrict__ ut_w2, const float* __restrict__ ut_b2,
    const float* __restrict__ it_cont_w, const float* __restrict__ it_cont_b,
    const float* __restrict__ it_w1, const float* __restrict__ it_b1,
    const float* __restrict__ it_g,  const float* __restrict__ it_be,
    const float* __restrict__ it_w2, const float* __restrict__ it_b2,
    float* __restrict__ out, int B)
{
    const int tid  = threadIdx.x;
    const int wave = tid >> 6;
    const int lane = tid & 63;
    const int r0   = blockIdx.x * R;

    __shared__ float s_x[R * 256];    // 16KB: x rows; first R*128 reused as h
    __shared__ float s_w[128 * 33];   // 16.9KB: weight chunk (padded rows)
    float* hs = s_x;                  // alias (guarded by barriers)

    //---------------- user features -> s_x [16][256] ----------------
    #pragma unroll
    for (int j = 0; j < RPW; ++j) {
        const int lr = wave * RPW + j;
        const int b  = r0 + lr;
        const float u_e = emb_user[(size_t)user_id[b] * DD + lane];
        const float hp  = hist_pool[(size_t)b * DD + lane];
        const int* grow = top_genres + (size_t)b * GG;
        float gacc = 0.f, gw = 0.f;
        #pragma unroll
        for (int g = 0; g < GG; ++g) {
            const int idx = grow[g];
            const float m = (idx > 0) ? 1.f : 0.f;
            gacc = fmaf(m, emb_genre[idx * DD + lane], gacc);
            gw  += m;
        }
        const float ua = u_avg[b], av = activity[b];
        float uc = fmaf(ua, ut_cont_w[lane * 2 + 0],
                   fmaf(av, ut_cont_w[lane * 2 + 1], ut_cont_b[lane]));
        uc = fmaxf(uc, 0.f);
        s_x[lr * 256 + lane]       = u_e;
        s_x[lr * 256 + 64 + lane]  = hp;
        s_x[lr * 256 + 128 + lane] = gacc / (gw + 1e-8f);
        s_x[lr * 256 + 192 + lane] = uc;
    }
    __syncthreads();

    //---------------- user layer 1: [256]->[128] ----------------
    float y0[RPW], y1[RPW];
    {
        const float b0 = ut_b1[lane], b1v = ut_b1[lane + 64];
        #pragma unroll
        for (int j = 0; j < RPW; ++j) { y0[j] = b0; y1[j] = b1v; }
    }
    for (int c = 0; c < 8; ++c) {                 // 8 chunks of 32 k's
        for (int t = tid; t < 128 * 32; t += 256) {
            const int n = t >> 5, kk = t & 31;
            s_w[n * 33 + kk] = ut_w1[n * 256 + c * 32 + kk];
        }
        __syncthreads();
        #pragma unroll
        for (int kk4 = 0; kk4 < 8; ++kk4) {
            float4 xv[RPW];
            #pragma unroll
            for (int j = 0; j < RPW; ++j)
                xv[j] = *(const float4*)&s_x[(wave * RPW + j) * 256 + c * 32 + kk4 * 4];
            #pragma unroll
            for (int t = 0; t < 4; ++t) {
                const int kk = kk4 * 4 + t;
                const float w0 = s_w[lane * 33 + kk];
                const float w1 = s_w[(lane + 64) * 33 + kk];
                #pragma unroll
                for (int j = 0; j < RPW; ++j) {
                    const float xk = ((const float*)&xv[j])[t];
                    y0[j] = fmaf(xk, w0, y0[j]);
                    y1[j] = fmaf(xk, w1, y1[j]);
                }
            }
        }
        __syncthreads();
    }
    //---------------- user LN + ReLU -> hs ----------------
    {
        const float g0 = ut_g[lane], g1 = ut_g[lane + 64];
        const float e0 = ut_be[lane], e1 = ut_be[lane + 64];
        #pragma unroll
        for (int j = 0; j < RPW; ++j) {
            const float mean = wave_reduce_sum(y0[j] + y1[j]) * (1.f / 128.f);
            const float d0 = y0[j] - mean, d1 = y1[j] - mean;
            const float var = wave_reduce_sum(d0 * d0 + d1 * d1) * (1.f / 128.f);
            const float rstd = rsqrtf(var + 1e-5f);
            y0[j] = fmaxf(fmaf(d0 * rstd, g0, e0), 0.f);
            y1[j] = fmaxf(fmaf(d1 * rstd, g1, e1), 0.f);
        }
    }
    #pragma unroll
    for (int j = 0; j < RPW; ++j) {
        hs[(wave * RPW + j) * 128 + lane]      = y0[j];
        hs[(wave * RPW + j) * 128 + 64 + lane] = y1[j];
    }
    __syncthreads();

    //---------------- user layer 2: [128]->[64], l2norm, store ----------------
    float y2[RPW];
    {
        const float b2 = ut_b2[lane];
        #pragma unroll
        for (int j = 0; j < RPW; ++j) y2[j] = b2;
    }
    for (int c = 0; c < 2; ++c) {                 // 2 chunks of 64 k's
        for (int t = tid; t < 64 * 64; t += 256) {
            const int m = t >> 6, kk = t & 63;
            s_w[m * 65 + kk] = ut_w2[m * 128 + c * 64 + kk];
        }
        __syncthreads();
        #pragma unroll
        for (int kk4 = 0; kk4 < 16; ++kk4) {
            float4 hv[RPW];
            #pragma unroll
            for (int j = 0; j < RPW; ++j)
                hv[j] = *(const float4*)&hs[(wave * RPW + j) * 128 + c * 64 + kk4 * 4];
            #pragma unroll
            for (int t = 0; t < 4; ++t) {
                const float w = s_w[lane * 65 + kk4 * 4 + t];
                #pragma unroll
                for (int j = 0; j < RPW; ++j)
                    y2[j] = fmaf(((const float*)&hv[j])[t], w, y2[j]);
            }
        }
        __syncthreads();
    }
    #pragma unroll
    for (int j = 0; j < RPW; ++j) {
        const int b = r0 + wave * RPW + j;
        const float nrm = sqrtf(wave_reduce_sum(y2[j] * y2[j]));
        out[(size_t)b * DD + lane] = y2[j] / fmaxf(nrm, 1e-12f);
    }
    __syncthreads();   // everyone done with hs before item restage

    //---------------- item features -> s_x [16][192] ----------------
    #pragma unroll
    for (int j = 0; j < RPW; ++j) {
        const int lr = wave * RPW + j;
        const int b  = r0 + lr;
        const float i_e = emb_item[(size_t)item_id[b] * DD + lane];
        const int* grow = tmdb_genres + (size_t)b * GG;
        float gacc = 0.f, gw = 0.f;
        #pragma unroll
        for (int g = 0; g < GG; ++g) {
            const int idx = grow[g];
            const float m = (idx > 0) ? 1.f : 0.f;
            gacc = fmaf(m, emb_genre[idx * DD + lane], gacc);
            gw  += m;
        }
        const float r1 = rel_year[b], r2 = i_avg[b], r3 = revenue[b];
        float ic = fmaf(r1, it_cont_w[lane * 3 + 0],
                   fmaf(r2, it_cont_w[lane * 3 + 1],
                   fmaf(r3, it_cont_w[lane * 3 + 2], it_cont_b[lane])));
        ic = fmaxf(ic, 0.f);
        s_x[lr * 192 + lane]       = i_e;
        s_x[lr * 192 + 64 + lane]  = gacc / (gw + 1e-8f);
        s_x[lr * 192 + 128 + lane] = ic;
    }
    __syncthreads();

    //---------------- item layer 1: [192]->[128] ----------------
    {
        const float b0 = it_b1[lane], b1v = it_b1[lane + 64];
        #pragma unroll
        for (int j = 0; j < RPW; ++j) { y0[j] = b0; y1[j] = b1v; }
    }
    for (int c = 0; c < 6; ++c) {                 // 6 chunks of 32 k's
        for (int t = tid; t < 128 * 32; t += 256) {
            const int n = t >> 5, kk = t & 31;
            s_w[n * 33 + kk] = it_w1[n * 192 + c * 32 + kk];
        }
        __syncthreads();
        #pragma unroll
        for (int kk4 = 0; kk4 < 8; ++kk4) {
            float4 xv[RPW];
            #pragma unroll
            for (int j = 0; j < RPW; ++j)
                xv[j] = *(const float4*)&s_x[(wave * RPW + j) * 192 + c * 32 + kk4 * 4];
            #pragma unroll
            for (int t = 0; t < 4; ++t) {
                const int kk = kk4 * 4 + t;
                const float w0 = s_w[lane * 33 + kk];
                const float w1 = s_w[(lane + 64) * 33 + kk];
                #pragma unroll
                for (int j = 0; j < RPW; ++j) {
                    const float xk = ((const float*)&xv[j])[t];
                    y0[j] = fmaf(xk, w0, y0[j]);
                    y1[j] = fmaf(xk, w1, y1[j]);
                }
            }
        }
        __syncthreads();
    }
    //---------------- item LN + ReLU -> hs ----------------
    {
        const float g0 = it_g[lane], g1 = it_g[lane + 64];
        const float e0 = it_be[lane], e1 = it_be[lane + 64];
        #pragma unroll
        for (int j = 0; j < RPW; ++j) {
            const float mean = wave_reduce_sum(y0[j] + y1[j]) * (1.f / 128.f);
            const float d0 = y0[j] - mean, d1 = y1[j] - mean;
            const float var = wave_reduce_sum(d0 * d0 + d1 * d1) * (1.f / 128.f);
            const float rstd = rsqrtf(var + 1e-5f);
            y0[j] = fmaxf(fmaf(d0 * rstd, g0, e0), 0.f);
            y1[j] = fmaxf(fmaf(d1 * rstd, g1, e1), 0.f);
        }
    }
    #pragma unroll
    for (int j = 0; j < RPW; ++j) {
        hs[(wave * RPW + j) * 128 + lane]      = y0[j];
        hs[(wave * RPW + j) * 128 + 64 + lane] = y1[j];
    }
    __syncthreads();

    //---------------- item layer 2 + l2norm + store ----------------
    {
        const float b2 = it_b2[lane];
        #pragma unroll
        for (int j = 0; j < RPW; ++j) y2[j] = b2;
    }
    for (int c = 0; c < 2; ++c) {
        for (int t = tid; t < 64 * 64; t += 256) {
            const int m = t >> 6, kk = t & 63;
            s_w[m * 65 + kk] = it_w2[m * 128 + c * 64 + kk];
        }
        __syncthreads();
        #pragma unroll
        for (int kk4 = 0; kk4 < 16; ++kk4) {
            float4 hv[RPW];
            #pragma unroll
            for (int j = 0; j < RPW; ++j)
                hv[j] = *(const float4*)&hs[(wave * RPW + j) * 128 + c * 64 + kk4 * 4];
            #pragma unroll
            for (int t = 0; t < 4; ++t) {
                const float w = s_w[lane * 65 + kk4 * 4 + t];
                #pragma unroll
                for (int j = 0; j < RPW; ++j)
                    y2[j] = fmaf(((const float*)&hv[j])[t], w, y2[j]);
            }
        }
        __syncthreads();
    }
    #pragma unroll
    for (int j = 0; j < RPW; ++j) {
        const int b = r0 + wave * RPW + j;
        const float nrm = sqrtf(wave_reduce_sum(y2[j] * y2[j]));
        out[(size_t)B * DD + (size_t)b * DD + lane] = y2[j] / fmaxf(nrm, 1e-12f);
    }
}

extern "C" void kernel_launch(void* const* d_in, const int* in_sizes, int n_in,
                              void* d_out, int out_size, void* d_ws, size_t ws_size,
                              hipStream_t stream) {
    const int*   user_id     = (const int*)  d_in[0];
    const int*   history     = (const int*)  d_in[1];
    const int*   top_genres  = (const int*)  d_in[2];
    const int*   item_id     = (const int*)  d_in[3];
    const int*   tmdb_genres = (const int*)  d_in[4];
    const float* ts_diff     = (const float*)d_in[5];
    const float* u_avg       = (const float*)d_in[6];
    const float* activity    = (const float*)d_in[7];
    const float* rel_year    = (const float*)d_in[8];
    const float* i_avg       = (const float*)d_in[9];
    const float* revenue     = (const float*)d_in[10];
    const float* emb_item    = (const float*)d_in[11];
    const float* emb_genre   = (const float*)d_in[12];
    const float* emb_user    = (const float*)d_in[13];
    const float* ut_cont_w   = (const float*)d_in[14];
    const float* ut_cont_b   = (const float*)d_in[15];
    const float* ut_w1       = (const float*)d_in[16];
    const float* ut_b1       = (const float*)d_in[17];
    const float* ut_g        = (const float*)d_in[18];
    const float* ut_be       = (const float*)d_in[19];
    const float* ut_w2       = (const float*)d_in[20];
    const float* ut_b2       = (const float*)d_in[21];
    const float* it_cont_w   = (const float*)d_in[22];
    const float* it_cont_b   = (const float*)d_in[23];
    const float* it_w1       = (const float*)d_in[24];
    const float* it_b1       = (const float*)d_in[25];
    const float* it_g        = (const float*)d_in[26];
    const float* it_be       = (const float*)d_in[27];
    const float* it_w2       = (const float*)d_in[28];
    const float* it_b2       = (const float*)d_in[29];

    const int B = in_sizes[0];          // 16384
    float* hist_pool = (float*)d_ws;    // [B,64] = 4MB

    hipLaunchKernelGGL(hist_pool_kernel, dim3(B / 4), dim3(256), 0, stream,
        history, ts_diff, emb_item, hist_pool, B);

    hipLaunchKernelGGL(mlp_kernel, dim3(B / R), dim3(256), 0, stream,
        user_id, top_genres, item_id, tmdb_genres, hist_pool,
        u_avg, activity, rel_year, i_avg, revenue,
        emb_item, emb_genre, emb_user,
        ut_cont_w, ut_cont_b, ut_w1, ut_b1, ut_g, ut_be, ut_w2, ut_b2,
        it_cont_w, it_cont_b, it_w1, it_b1, it_g, it_be, it_w2, it_b2,
        (float*)d_out, B);
}

// Round 3
// 156.778 us; speedup vs baseline: 6.6763x; 1.6661x over previous
//
#include <hip/hip_runtime.h>

#define DD 64
#define LL 200
#define GG 6
#define LAMBDA 0.001f

typedef __attribute__((ext_vector_type(8))) short s8v;   // 8 bf16 (4 VGPRs)
typedef __attribute__((ext_vector_type(4))) float f4v;   // MFMA accumulator

__device__ __forceinline__ float wave_reduce_sum(float v) {
    #pragma unroll
    for (int off = 32; off > 0; off >>= 1)
        v += __shfl_xor(v, off, 64);
    return v;
}

__device__ __forceinline__ unsigned short f2bf(float f) {
    union { float f; unsigned int u; } v; v.f = f;
    return (unsigned short)((v.u + 0x7FFFu + ((v.u >> 16) & 1u)) >> 16);  // RNE
}

//======================================================================
// Kernel 1: history pooling. One wave per row, 4 waves/block.
//======================================================================
__global__ __launch_bounds__(256)
void hist_pool_kernel(const int* __restrict__ history,
                      const float* __restrict__ ts_diff,
                      const float* __restrict__ emb_item,
                      float* __restrict__ hist_out, int B)
{
    const int wave = threadIdx.x >> 6;
    const int lane = threadIdx.x & 63;
    const int b = blockIdx.x * 4 + wave;

    __shared__ float2 s_p[4][LL];

    const int*   hrow = history + (size_t)b * LL;
    const float* trow = ts_diff + (size_t)b * LL;

    float wpart = 0.f;
    for (int l = lane; l < LL; l += 64) {
        const int idx = hrow[l];
        const float w = (idx > 0) ? __expf(-LAMBDA * trow[l]) : 0.f;
        s_p[wave][l] = make_float2(w, __int_as_float(idx));
        wpart += w;
    }
    const float wsum = wave_reduce_sum(wpart);
    __syncthreads();

    float acc = 0.f;
    #pragma unroll 1
    for (int l0 = 0; l0 < LL; l0 += 8) {
        float e[8], w[8];
        #pragma unroll
        for (int i = 0; i < 8; ++i) {
            const float2 p = s_p[wave][l0 + i];
            w[i] = p.x;
            e[i] = emb_item[(size_t)__float_as_int(p.y) * DD + lane];
        }
        #pragma unroll
        for (int i = 0; i < 8; ++i) acc = fmaf(w[i], e[i], acc);
    }
    hist_out[(size_t)b * DD + lane] = acc / (wsum + 1e-8f);
}

//======================================================================
// Shared helpers for tower kernels
//======================================================================
// X/H fragment slot: A-operand layout for mfma_f32_16x16x32_bf16:
//   lane' = ((d>>3)&3)*16 + (r&15),  j = d&7,  k-step = d>>5
// stored as [(mt*NKS + ks)*64 + lane'] * 8 + j   (16B per lane slot)

#define PUT_FRAG(buf, NKS, r, d, val)                                   \
    do {                                                                \
        const int _mt = (r) >> 4, _ks = (d) >> 5;                       \
        const int _lp = (((d) >> 3) & 3) * 16 + ((r) & 15);             \
        (buf)[(((_mt) * (NKS) + _ks) * 64 + _lp) * 8 + ((d) & 7)] = f2bf(val); \
    } while (0)

//======================================================================
// Kernel 2: user tower (K1=256 -> 128 -> 64), 64 rows/block, 4 waves.
//======================================================================
__global__ __launch_bounds__(256)
void user_tower_kernel(
    const int* __restrict__ user_id, const int* __restrict__ top_genres,
    const float* __restrict__ hist_pool,
    const float* __restrict__ u_avg, const float* __restrict__ activity,
    const float* __restrict__ emb_genre, const float* __restrict__ emb_user,
    const float* __restrict__ cont_w, const float* __restrict__ cont_b,
    const float* __restrict__ w1, const float* __restrict__ b1,
    const float* __restrict__ gam, const float* __restrict__ bet,
    const float* __restrict__ w2, const float* __restrict__ b2,
    float* __restrict__ out, int B)
{
    const int tid = threadIdx.x, wave = tid >> 6, lane = tid & 63;
    const int r0 = blockIdx.x * 64;

    __shared__ __align__(16) unsigned short sW1[8 * 8 * 64 * 8];  // 64KB frag-order
    __shared__ __align__(16) unsigned short sW2[4 * 4 * 64 * 8];  // 16KB frag-order
    __shared__ __align__(16) unsigned char  sC[64 * 128 * 4];     // 32KB: Xfrag -> y -> o
    __shared__ __align__(16) unsigned short sHf[4 * 4 * 64 * 8];  // 16KB h frag-order

    unsigned short* sXf = (unsigned short*)sC;   // 4mt * 8ks * 64 * 8 = 32KB
    float* sY = (float*)sC;                      // [64][128]
    float* sO = (float*)sC;                      // [64][64]

    //---- stage W1 -> frag order (bf16) ----
    {
        const int r = tid >> 1, half = tid & 1;
        #pragma unroll
        for (int c = 0; c < 16; ++c) {
            const int k = half * 128 + c * 8;
            const float4 f0 = *(const float4*)&w1[r * 256 + k];
            const float4 f1 = *(const float4*)&w1[r * 256 + k + 4];
            const int ks = k >> 5, lg = (k >> 3) & 3;
            const int lp = lg * 16 + (r & 15), nt = r >> 4;
            s8v wv;
            wv[0] = (short)f2bf(f0.x); wv[1] = (short)f2bf(f0.y);
            wv[2] = (short)f2bf(f0.z); wv[3] = (short)f2bf(f0.w);
            wv[4] = (short)f2bf(f1.x); wv[5] = (short)f2bf(f1.y);
            wv[6] = (short)f2bf(f1.z); wv[7] = (short)f2bf(f1.w);
            *(s8v*)&sW1[((ks * 8 + nt) * 64 + lp) * 8] = wv;
        }
    }
    //---- stage W2 -> frag order ----
    {
        const int r = tid & 63, cb = (tid >> 6) * 4;
        #pragma unroll
        for (int c = cb; c < cb + 4; ++c) {
            const int k = c * 8;
            const float4 f0 = *(const float4*)&w2[r * 128 + k];
            const float4 f1 = *(const float4*)&w2[r * 128 + k + 4];
            const int ks = k >> 5, lg = (k >> 3) & 3;
            const int lp = lg * 16 + (r & 15), nt = r >> 4;
            s8v wv;
            wv[0] = (short)f2bf(f0.x); wv[1] = (short)f2bf(f0.y);
            wv[2] = (short)f2bf(f0.z); wv[3] = (short)f2bf(f0.w);
            wv[4] = (short)f2bf(f1.x); wv[5] = (short)f2bf(f1.y);
            wv[6] = (short)f2bf(f1.z); wv[7] = (short)f2bf(f1.w);
            *(s8v*)&sW2[((ks * 4 + nt) * 64 + lp) * 8] = wv;
        }
    }
    //---- build X features (wave -> rows wave*16..+15) ----
    #pragma unroll 2
    for (int i = 0; i < 16; ++i) {
        const int r = wave * 16 + i, b = r0 + r;
        const float ue = emb_user[(size_t)user_id[b] * DD + lane];
        const float hp = hist_pool[(size_t)b * DD + lane];
        const int* grow = top_genres + (size_t)b * GG;
        float gacc = 0.f, gw = 0.f;
        #pragma unroll
        for (int g = 0; g < GG; ++g) {
            const int idx = grow[g];
            const float m = (idx > 0) ? 1.f : 0.f;
            gacc = fmaf(m, emb_genre[idx * DD + lane], gacc);
            gw += m;
        }
        const float ug = gacc / (gw + 1e-8f);
        float uc = fmaf(u_avg[b], cont_w[lane * 2 + 0],
                   fmaf(activity[b], cont_w[lane * 2 + 1], cont_b[lane]));
        uc = fmaxf(uc, 0.f);
        PUT_FRAG(sXf, 8, r, lane, ue);
        PUT_FRAG(sXf, 8, r, 64 + lane, hp);
        PUT_FRAG(sXf, 8, r, 128 + lane, ug);
        PUT_FRAG(sXf, 8, r, 192 + lane, uc);
    }
    __syncthreads();

    //---- L1 MFMA: M=64, N=128, K=256. wave: mh=wave>>1 (2 mtiles), nh=wave&1 (4 ntiles)
    const int mh = wave >> 1, nh = wave & 1;
    f4v acc[2][4];
    const f4v zero4 = {0.f, 0.f, 0.f, 0.f};
    #pragma unroll
    for (int a = 0; a < 2; ++a)
        #pragma unroll
        for (int c = 0; c < 4; ++c) acc[a][c] = zero4;

    #pragma unroll
    for (int ks = 0; ks < 8; ++ks) {
        s8v av[2], bv[4];
        #pragma unroll
        for (int ml = 0; ml < 2; ++ml)
            av[ml] = *(const s8v*)&sXf[(((mh * 2 + ml) * 8 + ks) * 64 + lane) * 8];
        #pragma unroll
        for (int nl = 0; nl < 4; ++nl)
            bv[nl] = *(const s8v*)&sW1[((ks * 8 + nh * 4 + nl) * 64 + lane) * 8];
        #pragma unroll
        for (int ml = 0; ml < 2; ++ml)
            #pragma unroll
            for (int nl = 0; nl < 4; ++nl)
                acc[ml][nl] = __builtin_amdgcn_mfma_f32_16x16x32_bf16(av[ml], bv[nl], acc[ml][nl], 0, 0, 0);
    }
    __syncthreads();   // all waves done reading sXf

    //---- y = acc + b1 -> sY [64][128] fp32 ----
    #pragma unroll
    for (int ml = 0; ml < 2; ++ml) {
        #pragma unroll
        for (int nl = 0; nl < 4; ++nl) {
            const int n = (nh * 4 + nl) * 16 + (lane & 15);
            const float bb = b1[n];
            #pragma unroll
            for (int rg = 0; rg < 4; ++rg) {
                const int m = (mh * 2 + ml) * 16 + (lane >> 4) * 4 + rg;
                sY[m * 128 + n] = acc[ml][nl][rg] + bb;
            }
        }
    }
    __syncthreads();

    //---- LN + ReLU -> sHf (bf16 frag order) ----
    {
        const float g0 = gam[lane], g1 = gam[lane + 64];
        const float e0 = bet[lane], e1 = bet[lane + 64];
        for (int i = 0; i < 16; ++i) {
            const int r = wave * 16 + i;
            const float a = sY[r * 128 + lane];
            const float c = sY[r * 128 + 64 + lane];
            const float mean = wave_reduce_sum(a + c) * (1.f / 128.f);
            const float da = a - mean, dc = c - mean;
            const float var = wave_reduce_sum(da * da + dc * dc) * (1.f / 128.f);
            const float rstd = rsqrtf(var + 1e-5f);
            const float h0 = fmaxf(fmaf(da * rstd, g0, e0), 0.f);
            const float h1 = fmaxf(fmaf(dc * rstd, g1, e1), 0.f);
            PUT_FRAG(sHf, 4, r, lane, h0);
            PUT_FRAG(sHf, 4, r, 64 + lane, h1);
        }
    }
    __syncthreads();

    //---- L2 MFMA: M=64, N=64, K=128. wave: mh (2 mtiles), nh (2 ntiles) ----
    f4v acc2[2][2];
    #pragma unroll
    for (int a = 0; a < 2; ++a)
        #pragma unroll
        for (int c = 0; c < 2; ++c) acc2[a][c] = zero4;

    #pragma unroll
    for (int ks = 0; ks < 4; ++ks) {
        s8v av[2], bv[2];
        #pragma unroll
        for (int ml = 0; ml < 2; ++ml)
            av[ml] = *(const s8v*)&sHf[(((mh * 2 + ml) * 4 + ks) * 64 + lane) * 8];
        #pragma unroll
        for (int nl = 0; nl < 2; ++nl)
            bv[nl] = *(const s8v*)&sW2[((ks * 4 + nh * 2 + nl) * 64 + lane) * 8];
        #pragma unroll
        for (int ml = 0; ml < 2; ++ml)
            #pragma unroll
            for (int nl = 0; nl < 2; ++nl)
                acc2[ml][nl] = __builtin_amdgcn_mfma_f32_16x16x32_bf16(av[ml], bv[nl], acc2[ml][nl], 0, 0, 0);
    }
    //---- o = acc2 + b2 -> sO [64][64] (region free since LN barrier) ----
    #pragma unroll
    for (int ml = 0; ml < 2; ++ml) {
        #pragma unroll
        for (int nl = 0; nl < 2; ++nl) {
            const int n = (nh * 2 + nl) * 16 + (lane & 15);
            const float bb = b2[n];
            #pragma unroll
            for (int rg = 0; rg < 4; ++rg) {
                const int m = (mh * 2 + ml) * 16 + (lane >> 4) * 4 + rg;
                sO[m * 64 + n] = acc2[ml][nl][rg] + bb;
            }
        }
    }
    __syncthreads();

    //---- l2norm + store ----
    for (int i = 0; i < 16; ++i) {
        const int r = wave * 16 + i;
        const float o = sO[r * 64 + lane];
        const float nrm = sqrtf(wave_reduce_sum(o * o));
        out[(size_t)(r0 + r) * DD + lane] = o / fmaxf(nrm, 1e-12f);
    }
}

//======================================================================
// Kernel 3: item tower (K1=192 -> 128 -> 64), 64 rows/block, 4 waves.
//======================================================================
__global__ __launch_bounds__(256)
void item_tower_kernel(
    const int* __restrict__ item_id, const int* __restrict__ tmdb_genres,
    const float* __restrict__ rel_year, const float* __restrict__ i_avg,
    const float* __restrict__ revenue,
    const float* __restrict__ emb_item, const float* __restrict__ emb_genre,
    const float* __restrict__ cont_w, const float* __restrict__ cont_b,
    const float* __restrict__ w1, const float* __restrict__ b1,
    const float* __restrict__ gam, const float* __restrict__ bet,
    const float* __restrict__ w2, const float* __restrict__ b2,
    float* __restrict__ out, int B)
{
    const int tid = threadIdx.x, wave = tid >> 6, lane = tid & 63;
    const int r0 = blockIdx.x * 64;

    __shared__ __align__(16) unsigned short sW1[6 * 8 * 64 * 8];  // 48KB
    __shared__ __align__(16) unsigned short sW2[4 * 4 * 64 * 8];  // 16KB
    __shared__ __align__(16) unsigned char  sC[64 * 128 * 4];     // 32KB: Xfrag -> y -> o
    __shared__ __align__(16) unsigned short sHf[4 * 4 * 64 * 8];  // 16KB

    unsigned short* sXf = (unsigned short*)sC;   // 4mt * 6ks * 64 * 8 = 24KB
    float* sY = (float*)sC;
    float* sO = (float*)sC;

    //---- stage W1 [128][192] -> frag order ----
    {
        const int r = tid >> 1, half = tid & 1;
        #pragma unroll
        for (int c = 0; c < 12; ++c) {
            const int k = half * 96 + c * 8;
            const float4 f0 = *(const float4*)&w1[r * 192 + k];
            const float4 f1 = *(const float4*)&w1[r * 192 + k + 4];
            const int ks = k >> 5, lg = (k >> 3) & 3;
            const int lp = lg * 16 + (r & 15), nt = r >> 4;
            s8v wv;
            wv[0] = (short)f2bf(f0.x); wv[1] = (short)f2bf(f0.y);
            wv[2] = (short)f2bf(f0.z); wv[3] = (short)f2bf(f0.w);
            wv[4] = (short)f2bf(f1.x); wv[5] = (short)f2bf(f1.y);
            wv[6] = (short)f2bf(f1.z); wv[7] = (short)f2bf(f1.w);
            *(s8v*)&sW1[((ks * 8 + nt) * 64 + lp) * 8] = wv;
        }
    }
    //---- stage W2 [64][128] -> frag order ----
    {
        const int r = tid & 63, cb = (tid >> 6) * 4;
        #pragma unroll
        for (int c = cb; c < cb + 4; ++c) {
            const int k = c * 8;
            const float4 f0 = *(const float4*)&w2[r * 128 + k];
            const float4 f1 = *(const float4*)&w2[r * 128 + k + 4];
            const int ks = k >> 5, lg = (k >> 3) & 3;
            const int lp = lg * 16 + (r & 15), nt = r >> 4;
            s8v wv;
            wv[0] = (short)f2bf(f0.x); wv[1] = (short)f2bf(f0.y);
            wv[2] = (short)f2bf(f0.z); wv[3] = (short)f2bf(f0.w);
            wv[4] = (short)f2bf(f1.x); wv[5] = (short)f2bf(f1.y);
            wv[6] = (short)f2bf(f1.z); wv[7] = (short)f2bf(f1.w);
            *(s8v*)&sW2[((ks * 4 + nt) * 64 + lp) * 8] = wv;
        }
    }
    //---- build X features ----
    #pragma unroll 2
    for (int i = 0; i < 16; ++i) {
        const int r = wave * 16 + i, b = r0 + r;
        const float ie = emb_item[(size_t)item_id[b] * DD + lane];
        const int* grow = tmdb_genres + (size_t)b * GG;
        float gacc = 0.f, gw = 0.f;
        #pragma unroll
        for (int g = 0; g < GG; ++g) {
            const int idx = grow[g];
            const float m = (idx > 0) ? 1.f : 0.f;
            gacc = fmaf(m, emb_genre[idx * DD + lane], gacc);
            gw += m;
        }
        const float ig = gacc / (gw + 1e-8f);
        float ic = fmaf(rel_year[b], cont_w[lane * 3 + 0],
                   fmaf(i_avg[b],   cont_w[lane * 3 + 1],
                   fmaf(revenue[b], cont_w[lane * 3 + 2], cont_b[lane])));
        ic = fmaxf(ic, 0.f);
        PUT_FRAG(sXf, 6, r, lane, ie);
        PUT_FRAG(sXf, 6, r, 64 + lane, ig);
        PUT_FRAG(sXf, 6, r, 128 + lane, ic);
    }
    __syncthreads();

    //---- L1 MFMA: M=64, N=128, K=192 ----
    const int mh = wave >> 1, nh = wave & 1;
    f4v acc[2][4];
    const f4v zero4 = {0.f, 0.f, 0.f, 0.f};
    #pragma unroll
    for (int a = 0; a < 2; ++a)
        #pragma unroll
        for (int c = 0; c < 4; ++c) acc[a][c] = zero4;

    #pragma unroll
    for (int ks = 0; ks < 6; ++ks) {
        s8v av[2], bv[4];
        #pragma unroll
        for (int ml = 0; ml < 2; ++ml)
            av[ml] = *(const s8v*)&sXf[(((mh * 2 + ml) * 6 + ks) * 64 + lane) * 8];
        #pragma unroll
        for (int nl = 0; nl < 4; ++nl)
            bv[nl] = *(const s8v*)&sW1[((ks * 8 + nh * 4 + nl) * 64 + lane) * 8];
        #pragma unroll
        for (int ml = 0; ml < 2; ++ml)
            #pragma unroll
            for (int nl = 0; nl < 4; ++nl)
                acc[ml][nl] = __builtin_amdgcn_mfma_f32_16x16x32_bf16(av[ml], bv[nl], acc[ml][nl], 0, 0, 0);
    }
    __syncthreads();

    #pragma unroll
    for (int ml = 0; ml < 2; ++ml) {
        #pragma unroll
        for (int nl = 0; nl < 4; ++nl) {
            const int n = (nh * 4 + nl) * 16 + (lane & 15);
            const float bb = b1[n];
            #pragma unroll
            for (int rg = 0; rg < 4; ++rg) {
                const int m = (mh * 2 + ml) * 16 + (lane >> 4) * 4 + rg;
                sY[m * 128 + n] = acc[ml][nl][rg] + bb;
            }
        }
    }
    __syncthreads();

    {
        const float g0 = gam[lane], g1 = gam[lane + 64];
        const float e0 = bet[lane], e1 = bet[lane + 64];
        for (int i = 0; i < 16; ++i) {
            const int r = wave * 16 + i;
            const float a = sY[r * 128 + lane];
            const float c = sY[r * 128 + 64 + lane];
            const float mean = wave_reduce_sum(a + c) * (1.f / 128.f);
            const float da = a - mean, dc = c - mean;
            const float var = wave_reduce_sum(da * da + dc * dc) * (1.f / 128.f);
            const float rstd = rsqrtf(var + 1e-5f);
            const float h0 = fmaxf(fmaf(da * rstd, g0, e0), 0.f);
            const float h1 = fmaxf(fmaf(dc * rstd, g1, e1), 0.f);
            PUT_FRAG(sHf, 4, r, lane, h0);
            PUT_FRAG(sHf, 4, r, 64 + lane, h1);
        }
    }
    __syncthreads();

    f4v acc2[2][2];
    #pragma unroll
    for (int a = 0; a < 2; ++a)
        #pragma unroll
        for (int c = 0; c < 2; ++c) acc2[a][c] = zero4;

    #pragma unroll
    for (int ks = 0; ks < 4; ++ks) {
        s8v av[2], bv[2];
        #pragma unroll
        for (int ml = 0; ml < 2; ++ml)
            av[ml] = *(const s8v*)&sHf[(((mh * 2 + ml) * 4 + ks) * 64 + lane) * 8];
        #pragma unroll
        for (int nl = 0; nl < 2; ++nl)
            bv[nl] = *(const s8v*)&sW2[((ks * 4 + nh * 2 + nl) * 64 + lane) * 8];
        #pragma unroll
        for (int ml = 0; ml < 2; ++ml)
            #pragma unroll
            for (int nl = 0; nl < 2; ++nl)
                acc2[ml][nl] = __builtin_amdgcn_mfma_f32_16x16x32_bf16(av[ml], bv[nl], acc2[ml][nl], 0, 0, 0);
    }
    #pragma unroll
    for (int ml = 0; ml < 2; ++ml) {
        #pragma unroll
        for (int nl = 0; nl < 2; ++nl) {
            const int n = (nh * 2 + nl) * 16 + (lane & 15);
            const float bb = b2[n];
            #pragma unroll
            for (int rg = 0; rg < 4; ++rg) {
                const int m = (mh * 2 + ml) * 16 + (lane >> 4) * 4 + rg;
                sO[m * 64 + n] = acc2[ml][nl][rg] + bb;
            }
        }
    }
    __syncthreads();

    for (int i = 0; i < 16; ++i) {
        const int r = wave * 16 + i;
        const float o = sO[r * 64 + lane];
        const float nrm = sqrtf(wave_reduce_sum(o * o));
        out[(size_t)B * DD + (size_t)(r0 + r) * DD + lane] = o / fmaxf(nrm, 1e-12f);
    }
}

extern "C" void kernel_launch(void* const* d_in, const int* in_sizes, int n_in,
                              void* d_out, int out_size, void* d_ws, size_t ws_size,
                              hipStream_t stream) {
    const int*   user_id     = (const int*)  d_in[0];
    const int*   history     = (const int*)  d_in[1];
    const int*   top_genres  = (const int*)  d_in[2];
    const int*   item_id     = (const int*)  d_in[3];
    const int*   tmdb_genres = (const int*)  d_in[4];
    const float* ts_diff     = (const float*)d_in[5];
    const float* u_avg       = (const float*)d_in[6];
    const float* activity    = (const float*)d_in[7];
    const float* rel_year    = (const float*)d_in[8];
    const float* i_avg       = (const float*)d_in[9];
    const float* revenue     = (const float*)d_in[10];
    const float* emb_item    = (const float*)d_in[11];
    const float* emb_genre   = (const float*)d_in[12];
    const float* emb_user    = (const float*)d_in[13];
    const float* ut_cont_w   = (const float*)d_in[14];
    const float* ut_cont_b   = (const float*)d_in[15];
    const float* ut_w1       = (const float*)d_in[16];
    const float* ut_b1       = (const float*)d_in[17];
    const float* ut_g        = (const float*)d_in[18];
    const float* ut_be       = (const float*)d_in[19];
    const float* ut_w2       = (const float*)d_in[20];
    const float* ut_b2       = (const float*)d_in[21];
    const float* it_cont_w   = (const float*)d_in[22];
    const float* it_cont_b   = (const float*)d_in[23];
    const float* it_w1       = (const float*)d_in[24];
    const float* it_b1       = (const float*)d_in[25];
    const float* it_g        = (const float*)d_in[26];
    const float* it_be       = (const float*)d_in[27];
    const float* it_w2       = (const float*)d_in[28];
    const float* it_b2       = (const float*)d_in[29];

    const int B = in_sizes[0];          // 16384
    float* hist_pool = (float*)d_ws;    // [B,64] = 4MB

    hipLaunchKernelGGL(hist_pool_kernel, dim3(B / 4), dim3(256), 0, stream,
        history, ts_diff, emb_item, hist_pool, B);

    hipLaunchKernelGGL(user_tower_kernel, dim3(B / 64), dim3(256), 0, stream,
        user_id, top_genres, hist_pool, u_avg, activity,
        emb_genre, emb_user, ut_cont_w, ut_cont_b,
        ut_w1, ut_b1, ut_g, ut_be, ut_w2, ut_b2,
        (float*)d_out, B);

    hipLaunchKernelGGL(item_tower_kernel, dim3(B / 64), dim3(256), 0, stream,
        item_id, tmdb_genres, rel_year, i_avg, revenue,
        emb_item, emb_genre, it_cont_w, it_cont_b,
        it_w1, it_b1, it_g, it_be, it_w2, it_b2,
        (float*)d_out, B);
}

// Round 4
// 155.281 us; speedup vs baseline: 6.7407x; 1.0096x over previous
//
#include <hip/hip_runtime.h>

#define DD 64
#define LL 200
#define LP 224     // LL padded to multiple of 32
#define GG 6
#define LAMBDA 0.001f

typedef __attribute__((ext_vector_type(8))) short s8v;   // 8 bf16 (4 VGPRs)
typedef __attribute__((ext_vector_type(4))) float f4v;   // MFMA accumulator

__device__ __forceinline__ float wave_reduce_sum(float v) {
    #pragma unroll
    for (int off = 32; off > 0; off >>= 1)
        v += __shfl_xor(v, off, 64);
    return v;
}

__device__ __forceinline__ unsigned short f2bf(float f) {
    union { float f; unsigned int u; } v; v.f = f;
    return (unsigned short)((v.u + 0x7FFFu + ((v.u >> 16) & 1u)) >> 16);  // RNE
}

//======================================================================
// Kernel 1: history pooling. One wave per row, 4 waves/block.
// 4-wide gather: 16-lane groups, float4 per lane, 8 dwordx4 in flight.
//======================================================================
__global__ __launch_bounds__(256)
void hist_pool_kernel(const int* __restrict__ history,
                      const float* __restrict__ ts_diff,
                      const float* __restrict__ emb_item,
                      float* __restrict__ hist_out, int B)
{
    const int wave = threadIdx.x >> 6;
    const int lane = threadIdx.x & 63;
    const int b = blockIdx.x * 4 + wave;
    const int g = lane >> 4;      // entry subgroup 0..3
    const int c = lane & 15;      // float4 column within row

    __shared__ float2 s_p[4][LP];

    const int*   hrow = history + (size_t)b * LL;
    const float* trow = ts_diff + (size_t)b * LL;

    float wpart = 0.f;
    #pragma unroll
    for (int l = lane; l < LP; l += 64) {
        int idx = 0; float w = 0.f;
        if (l < LL) {
            const int raw = hrow[l];
            if (raw > 0) { w = __expf(-LAMBDA * trow[l]); idx = raw; }
        }
        s_p[wave][l] = make_float2(w, __int_as_float(idx));
        wpart += w;
    }
    const float wsum = wave_reduce_sum(wpart);
    __syncthreads();

    float4 acc = make_float4(0.f, 0.f, 0.f, 0.f);
    #pragma unroll 1
    for (int l0 = 0; l0 < LP; l0 += 32) {
        float4 e[8]; float w[8];
        #pragma unroll
        for (int i = 0; i < 8; ++i) {
            const float2 p = s_p[wave][l0 + i * 4 + g];
            w[i] = p.x;
            e[i] = *(const float4*)&emb_item[(size_t)__float_as_int(p.y) * DD + c * 4];
        }
        #pragma unroll
        for (int i = 0; i < 8; ++i) {
            acc.x = fmaf(w[i], e[i].x, acc.x);
            acc.y = fmaf(w[i], e[i].y, acc.y);
            acc.z = fmaf(w[i], e[i].z, acc.z);
            acc.w = fmaf(w[i], e[i].w, acc.w);
        }
    }
    // reduce across the 4 entry-subgroups (lanes differing in bits 4,5)
    #pragma unroll
    for (int off = 16; off <= 32; off <<= 1) {
        acc.x += __shfl_xor(acc.x, off, 64);
        acc.y += __shfl_xor(acc.y, off, 64);
        acc.z += __shfl_xor(acc.z, off, 64);
        acc.w += __shfl_xor(acc.w, off, 64);
    }
    if (g == 0) {
        const float inv = 1.f / (wsum + 1e-8f);
        float4 o = make_float4(acc.x * inv, acc.y * inv, acc.z * inv, acc.w * inv);
        *(float4*)&hist_out[(size_t)b * DD + c * 4] = o;
    }
}

//======================================================================
// Shared helpers for tower kernels
//======================================================================
// X/H fragment slot: A-operand layout for mfma_f32_16x16x32_bf16:
//   lane' = ((d>>3)&3)*16 + (r&15),  j = d&7,  k-step = d>>5
// stored as [(mt*NKS + ks)*64 + lane'] * 8 + j   (16B per lane slot)

#define PUT_FRAG(buf, NKS, r, d, val)                                   \
    do {                                                                \
        const int _mt = (r) >> 4, _ks = (d) >> 5;                       \
        const int _lp = (((d) >> 3) & 3) * 16 + ((r) & 15);             \
        (buf)[(((_mt) * (NKS) + _ks) * 64 + _lp) * 8 + ((d) & 7)] = f2bf(val); \
    } while (0)

//======================================================================
// Kernel 2: user tower (K1=256 -> 128 -> 64), 64 rows/block, 4 waves.
//======================================================================
__global__ __launch_bounds__(256)
void user_tower_kernel(
    const int* __restrict__ user_id, const int* __restrict__ top_genres,
    const float* __restrict__ hist_pool,
    const float* __restrict__ u_avg, const float* __restrict__ activity,
    const float* __restrict__ emb_genre, const float* __restrict__ emb_user,
    const float* __restrict__ cont_w, const float* __restrict__ cont_b,
    const float* __restrict__ w1, const float* __restrict__ b1,
    const float* __restrict__ gam, const float* __restrict__ bet,
    const float* __restrict__ w2, const float* __restrict__ b2,
    float* __restrict__ out, int B)
{
    const int tid = threadIdx.x, wave = tid >> 6, lane = tid & 63;
    const int r0 = blockIdx.x * 64;

    __shared__ __align__(16) unsigned short sW1[8 * 8 * 64 * 8];  // 64KB frag-order
    __shared__ __align__(16) unsigned short sW2[4 * 4 * 64 * 8];  // 16KB frag-order
    __shared__ __align__(16) unsigned char  sC[64 * 128 * 4];     // 32KB: Xfrag -> y -> o
    __shared__ __align__(16) unsigned short sHf[4 * 4 * 64 * 8];  // 16KB h frag-order

    unsigned short* sXf = (unsigned short*)sC;   // 4mt * 8ks * 64 * 8 = 32KB
    float* sY = (float*)sC;                      // [64][128]
    float* sO = (float*)sC;                      // [64][64]

    //---- stage W1 -> frag order (bf16) ----
    {
        const int r = tid >> 1, half = tid & 1;
        #pragma unroll
        for (int c = 0; c < 16; ++c) {
            const int k = half * 128 + c * 8;
            const float4 f0 = *(const float4*)&w1[r * 256 + k];
            const float4 f1 = *(const float4*)&w1[r * 256 + k + 4];
            const int ks = k >> 5, lg = (k >> 3) & 3;
            const int lp = lg * 16 + (r & 15), nt = r >> 4;
            s8v wv;
            wv[0] = (short)f2bf(f0.x); wv[1] = (short)f2bf(f0.y);
            wv[2] = (short)f2bf(f0.z); wv[3] = (short)f2bf(f0.w);
            wv[4] = (short)f2bf(f1.x); wv[5] = (short)f2bf(f1.y);
            wv[6] = (short)f2bf(f1.z); wv[7] = (short)f2bf(f1.w);
            *(s8v*)&sW1[((ks * 8 + nt) * 64 + lp) * 8] = wv;
        }
    }
    //---- stage W2 -> frag order ----
    {
        const int r = tid & 63, cb = (tid >> 6) * 4;
        #pragma unroll
        for (int c = cb; c < cb + 4; ++c) {
            const int k = c * 8;
            const float4 f0 = *(const float4*)&w2[r * 128 + k];
            const float4 f1 = *(const float4*)&w2[r * 128 + k + 4];
            const int ks = k >> 5, lg = (k >> 3) & 3;
            const int lp = lg * 16 + (r & 15), nt = r >> 4;
            s8v wv;
            wv[0] = (short)f2bf(f0.x); wv[1] = (short)f2bf(f0.y);
            wv[2] = (short)f2bf(f0.z); wv[3] = (short)f2bf(f0.w);
            wv[4] = (short)f2bf(f1.x); wv[5] = (short)f2bf(f1.y);
            wv[6] = (short)f2bf(f1.z); wv[7] = (short)f2bf(f1.w);
            *(s8v*)&sW2[((ks * 4 + nt) * 64 + lp) * 8] = wv;
        }
    }
    //---- build X features (wave -> rows wave*16..+15) ----
    #pragma unroll 2
    for (int i = 0; i < 16; ++i) {
        const int r = wave * 16 + i, b = r0 + r;
        const float ue = emb_user[(size_t)user_id[b] * DD + lane];
        const float hp = hist_pool[(size_t)b * DD + lane];
        const int* grow = top_genres + (size_t)b * GG;
        float gacc = 0.f, gw = 0.f;
        #pragma unroll
        for (int g = 0; g < GG; ++g) {
            const int idx = grow[g];
            const float m = (idx > 0) ? 1.f : 0.f;
            gacc = fmaf(m, emb_genre[idx * DD + lane], gacc);
            gw += m;
        }
        const float ug = gacc / (gw + 1e-8f);
        float uc = fmaf(u_avg[b], cont_w[lane * 2 + 0],
                   fmaf(activity[b], cont_w[lane * 2 + 1], cont_b[lane]));
        uc = fmaxf(uc, 0.f);
        PUT_FRAG(sXf, 8, r, lane, ue);
        PUT_FRAG(sXf, 8, r, 64 + lane, hp);
        PUT_FRAG(sXf, 8, r, 128 + lane, ug);
        PUT_FRAG(sXf, 8, r, 192 + lane, uc);
    }
    __syncthreads();

    //---- L1 MFMA: M=64, N=128, K=256 ----
    const int mh = wave >> 1, nh = wave & 1;
    f4v acc[2][4];
    const f4v zero4 = {0.f, 0.f, 0.f, 0.f};
    #pragma unroll
    for (int a = 0; a < 2; ++a)
        #pragma unroll
        for (int c = 0; c < 4; ++c) acc[a][c] = zero4;

    #pragma unroll
    for (int ks = 0; ks < 8; ++ks) {
        s8v av[2], bv[4];
        #pragma unroll
        for (int ml = 0; ml < 2; ++ml)
            av[ml] = *(const s8v*)&sXf[(((mh * 2 + ml) * 8 + ks) * 64 + lane) * 8];
        #pragma unroll
        for (int nl = 0; nl < 4; ++nl)
            bv[nl] = *(const s8v*)&sW1[((ks * 8 + nh * 4 + nl) * 64 + lane) * 8];
        #pragma unroll
        for (int ml = 0; ml < 2; ++ml)
            #pragma unroll
            for (int nl = 0; nl < 4; ++nl)
                acc[ml][nl] = __builtin_amdgcn_mfma_f32_16x16x32_bf16(av[ml], bv[nl], acc[ml][nl], 0, 0, 0);
    }
    __syncthreads();

    //---- y = acc + b1 -> sY [64][128] fp32 ----
    #pragma unroll
    for (int ml = 0; ml < 2; ++ml) {
        #pragma unroll
        for (int nl = 0; nl < 4; ++nl) {
            const int n = (nh * 4 + nl) * 16 + (lane & 15);
            const float bb = b1[n];
            #pragma unroll
            for (int rg = 0; rg < 4; ++rg) {
                const int m = (mh * 2 + ml) * 16 + (lane >> 4) * 4 + rg;
                sY[m * 128 + n] = acc[ml][nl][rg] + bb;
            }
        }
    }
    __syncthreads();

    //---- LN + ReLU -> sHf (bf16 frag order) ----
    {
        const float g0 = gam[lane], g1 = gam[lane + 64];
        const float e0 = bet[lane], e1 = bet[lane + 64];
        for (int i = 0; i < 16; ++i) {
            const int r = wave * 16 + i;
            const float a = sY[r * 128 + lane];
            const float c = sY[r * 128 + 64 + lane];
            const float mean = wave_reduce_sum(a + c) * (1.f / 128.f);
            const float da = a - mean, dc = c - mean;
            const float var = wave_reduce_sum(da * da + dc * dc) * (1.f / 128.f);
            const float rstd = rsqrtf(var + 1e-5f);
            const float h0 = fmaxf(fmaf(da * rstd, g0, e0), 0.f);
            const float h1 = fmaxf(fmaf(dc * rstd, g1, e1), 0.f);
            PUT_FRAG(sHf, 4, r, lane, h0);
            PUT_FRAG(sHf, 4, r, 64 + lane, h1);
        }
    }
    __syncthreads();

    //---- L2 MFMA: M=64, N=64, K=128 ----
    f4v acc2[2][2];
    #pragma unroll
    for (int a = 0; a < 2; ++a)
        #pragma unroll
        for (int c = 0; c < 2; ++c) acc2[a][c] = zero4;

    #pragma unroll
    for (int ks = 0; ks < 4; ++ks) {
        s8v av[2], bv[2];
        #pragma unroll
        for (int ml = 0; ml < 2; ++ml)
            av[ml] = *(const s8v*)&sHf[(((mh * 2 + ml) * 4 + ks) * 64 + lane) * 8];
        #pragma unroll
        for (int nl = 0; nl < 2; ++nl)
            bv[nl] = *(const s8v*)&sW2[((ks * 4 + nh * 2 + nl) * 64 + lane) * 8];
        #pragma unroll
        for (int ml = 0; ml < 2; ++ml)
            #pragma unroll
            for (int nl = 0; nl < 2; ++nl)
                acc2[ml][nl] = __builtin_amdgcn_mfma_f32_16x16x32_bf16(av[ml], bv[nl], acc2[ml][nl], 0, 0, 0);
    }
    #pragma unroll
    for (int ml = 0; ml < 2; ++ml) {
        #pragma unroll
        for (int nl = 0; nl < 2; ++nl) {
            const int n = (nh * 2 + nl) * 16 + (lane & 15);
            const float bb = b2[n];
            #pragma unroll
            for (int rg = 0; rg < 4; ++rg) {
                const int m = (mh * 2 + ml) * 16 + (lane >> 4) * 4 + rg;
                sO[m * 64 + n] = acc2[ml][nl][rg] + bb;
            }
        }
    }
    __syncthreads();

    //---- l2norm + store ----
    for (int i = 0; i < 16; ++i) {
        const int r = wave * 16 + i;
        const float o = sO[r * 64 + lane];
        const float nrm = sqrtf(wave_reduce_sum(o * o));
        out[(size_t)(r0 + r) * DD + lane] = o / fmaxf(nrm, 1e-12f);
    }
}

//======================================================================
// Kernel 3: item tower (K1=192 -> 128 -> 64), 64 rows/block, 4 waves.
//======================================================================
__global__ __launch_bounds__(256)
void item_tower_kernel(
    const int* __restrict__ item_id, const int* __restrict__ tmdb_genres,
    const float* __restrict__ rel_year, const float* __restrict__ i_avg,
    const float* __restrict__ revenue,
    const float* __restrict__ emb_item, const float* __restrict__ emb_genre,
    const float* __restrict__ cont_w, const float* __restrict__ cont_b,
    const float* __restrict__ w1, const float* __restrict__ b1,
    const float* __restrict__ gam, const float* __restrict__ bet,
    const float* __restrict__ w2, const float* __restrict__ b2,
    float* __restrict__ out, int B)
{
    const int tid = threadIdx.x, wave = tid >> 6, lane = tid & 63;
    const int r0 = blockIdx.x * 64;

    __shared__ __align__(16) unsigned short sW1[6 * 8 * 64 * 8];  // 48KB
    __shared__ __align__(16) unsigned short sW2[4 * 4 * 64 * 8];  // 16KB
    __shared__ __align__(16) unsigned char  sC[64 * 128 * 4];     // 32KB: Xfrag -> y -> o
    __shared__ __align__(16) unsigned short sHf[4 * 4 * 64 * 8];  // 16KB

    unsigned short* sXf = (unsigned short*)sC;
    float* sY = (float*)sC;
    float* sO = (float*)sC;

    //---- stage W1 [128][192] -> frag order ----
    {
        const int r = tid >> 1, half = tid & 1;
        #pragma unroll
        for (int c = 0; c < 12; ++c) {
            const int k = half * 96 + c * 8;
            const float4 f0 = *(const float4*)&w1[r * 192 + k];
            const float4 f1 = *(const float4*)&w1[r * 192 + k + 4];
            const int ks = k >> 5, lg = (k >> 3) & 3;
            const int lp = lg * 16 + (r & 15), nt = r >> 4;
            s8v wv;
            wv[0] = (short)f2bf(f0.x); wv[1] = (short)f2bf(f0.y);
            wv[2] = (short)f2bf(f0.z); wv[3] = (short)f2bf(f0.w);
            wv[4] = (short)f2bf(f1.x); wv[5] = (short)f2bf(f1.y);
            wv[6] = (short)f2bf(f1.z); wv[7] = (short)f2bf(f1.w);
            *(s8v*)&sW1[((ks * 8 + nt) * 64 + lp) * 8] = wv;
        }
    }
    //---- stage W2 [64][128] -> frag order ----
    {
        const int r = tid & 63, cb = (tid >> 6) * 4;
        #pragma unroll
        for (int c = cb; c < cb + 4; ++c) {
            const int k = c * 8;
            const float4 f0 = *(const float4*)&w2[r * 128 + k];
            const float4 f1 = *(const float4*)&w2[r * 128 + k + 4];
            const int ks = k >> 5, lg = (k >> 3) & 3;
            const int lp = lg * 16 + (r & 15), nt = r >> 4;
            s8v wv;
            wv[0] = (short)f2bf(f0.x); wv[1] = (short)f2bf(f0.y);
            wv[2] = (short)f2bf(f0.z); wv[3] = (short)f2bf(f0.w);
            wv[4] = (short)f2bf(f1.x); wv[5] = (short)f2bf(f1.y);
            wv[6] = (short)f2bf(f1.z); wv[7] = (short)f2bf(f1.w);
            *(s8v*)&sW2[((ks * 4 + nt) * 64 + lp) * 8] = wv;
        }
    }
    //---- build X features ----
    #pragma unroll 2
    for (int i = 0; i < 16; ++i) {
        const int r = wave * 16 + i, b = r0 + r;
        const float ie = emb_item[(size_t)item_id[b] * DD + lane];
        const int* grow = tmdb_genres + (size_t)b * GG;
        float gacc = 0.f, gw = 0.f;
        #pragma unroll
        for (int g = 0; g < GG; ++g) {
            const int idx = grow[g];
            const float m = (idx > 0) ? 1.f : 0.f;
            gacc = fmaf(m, emb_genre[idx * DD + lane], gacc);
            gw += m;
        }
        const float ig = gacc / (gw + 1e-8f);
        float ic = fmaf(rel_year[b], cont_w[lane * 3 + 0],
                   fmaf(i_avg[b],   cont_w[lane * 3 + 1],
                   fmaf(revenue[b], cont_w[lane * 3 + 2], cont_b[lane])));
        ic = fmaxf(ic, 0.f);
        PUT_FRAG(sXf, 6, r, lane, ie);
        PUT_FRAG(sXf, 6, r, 64 + lane, ig);
        PUT_FRAG(sXf, 6, r, 128 + lane, ic);
    }
    __syncthreads();

    //---- L1 MFMA: M=64, N=128, K=192 ----
    const int mh = wave >> 1, nh = wave & 1;
    f4v acc[2][4];
    const f4v zero4 = {0.f, 0.f, 0.f, 0.f};
    #pragma unroll
    for (int a = 0; a < 2; ++a)
        #pragma unroll
        for (int c = 0; c < 4; ++c) acc[a][c] = zero4;

    #pragma unroll
    for (int ks = 0; ks < 6; ++ks) {
        s8v av[2], bv[4];
        #pragma unroll
        for (int ml = 0; ml < 2; ++ml)
            av[ml] = *(const s8v*)&sXf[(((mh * 2 + ml) * 6 + ks) * 64 + lane) * 8];
        #pragma unroll
        for (int nl = 0; nl < 4; ++nl)
            bv[nl] = *(const s8v*)&sW1[((ks * 8 + nh * 4 + nl) * 64 + lane) * 8];
        #pragma unroll
        for (int ml = 0; ml < 2; ++ml)
            #pragma unroll
            for (int nl = 0; nl < 4; ++nl)
                acc[ml][nl] = __builtin_amdgcn_mfma_f32_16x16x32_bf16(av[ml], bv[nl], acc[ml][nl], 0, 0, 0);
    }
    __syncthreads();

    #pragma unroll
    for (int ml = 0; ml < 2; ++ml) {
        #pragma unroll
        for (int nl = 0; nl < 4; ++nl) {
            const int n = (nh * 4 + nl) * 16 + (lane & 15);
            const float bb = b1[n];
            #pragma unroll
            for (int rg = 0; rg < 4; ++rg) {
                const int m = (mh * 2 + ml) * 16 + (lane >> 4) * 4 + rg;
                sY[m * 128 + n] = acc[ml][nl][rg] + bb;
            }
        }
    }
    __syncthreads();

    {
        const float g0 = gam[lane], g1 = gam[lane + 64];
        const float e0 = bet[lane], e1 = bet[lane + 64];
        for (int i = 0; i < 16; ++i) {
            const int r = wave * 16 + i;
            const float a = sY[r * 128 + lane];
            const float c = sY[r * 128 + 64 + lane];
            const float mean = wave_reduce_sum(a + c) * (1.f / 128.f);
            const float da = a - mean, dc = c - mean;
            const float var = wave_reduce_sum(da * da + dc * dc) * (1.f / 128.f);
            const float rstd = rsqrtf(var + 1e-5f);
            const float h0 = fmaxf(fmaf(da * rstd, g0, e0), 0.f);
            const float h1 = fmaxf(fmaf(dc * rstd, g1, e1), 0.f);
            PUT_FRAG(sHf, 4, r, lane, h0);
            PUT_FRAG(sHf, 4, r, 64 + lane, h1);
        }
    }
    __syncthreads();

    f4v acc2[2][2];
    #pragma unroll
    for (int a = 0; a < 2; ++a)
        #pragma unroll
        for (int c = 0; c < 2; ++c) acc2[a][c] = zero4;

    #pragma unroll
    for (int ks = 0; ks < 4; ++ks) {
        s8v av[2], bv[2];
        #pragma unroll
        for (int ml = 0; ml < 2; ++ml)
            av[ml] = *(const s8v*)&sHf[(((mh * 2 + ml) * 4 + ks) * 64 + lane) * 8];
        #pragma unroll
        for (int nl = 0; nl < 2; ++nl)
            bv[nl] = *(const s8v*)&sW2[((ks * 4 + nh * 2 + nl) * 64 + lane) * 8];
        #pragma unroll
        for (int ml = 0; ml < 2; ++ml)
            #pragma unroll
            for (int nl = 0; nl < 2; ++nl)
                acc2[ml][nl] = __builtin_amdgcn_mfma_f32_16x16x32_bf16(av[ml], bv[nl], acc2[ml][nl], 0, 0, 0);
    }
    #pragma unroll
    for (int ml = 0; ml < 2; ++ml) {
        #pragma unroll
        for (int nl = 0; nl < 2; ++nl) {
            const int n = (nh * 2 + nl) * 16 + (lane & 15);
            const float bb = b2[n];
            #pragma unroll
            for (int rg = 0; rg < 4; ++rg) {
                const int m = (mh * 2 + ml) * 16 + (lane >> 4) * 4 + rg;
                sO[m * 64 + n] = acc2[ml][nl][rg] + bb;
            }
        }
    }
    __syncthreads();

    for (int i = 0; i < 16; ++i) {
        const int r = wave * 16 + i;
        const float o = sO[r * 64 + lane];
        const float nrm = sqrtf(wave_reduce_sum(o * o));
        out[(size_t)B * DD + (size_t)(r0 + r) * DD + lane] = o / fmaxf(nrm, 1e-12f);
    }
}

extern "C" void kernel_launch(void* const* d_in, const int* in_sizes, int n_in,
                              void* d_out, int out_size, void* d_ws, size_t ws_size,
                              hipStream_t stream) {
    const int*   user_id     = (const int*)  d_in[0];
    const int*   history     = (const int*)  d_in[1];
    const int*   top_genres  = (const int*)  d_in[2];
    const int*   item_id     = (const int*)  d_in[3];
    const int*   tmdb_genres = (const int*)  d_in[4];
    const float* ts_diff     = (const float*)d_in[5];
    const float* u_avg       = (const float*)d_in[6];
    const float* activity    = (const float*)d_in[7];
    const float* rel_year    = (const float*)d_in[8];
    const float* i_avg       = (const float*)d_in[9];
    const float* revenue     = (const float*)d_in[10];
    const float* emb_item    = (const float*)d_in[11];
    const float* emb_genre   = (const float*)d_in[12];
    const float* emb_user    = (const float*)d_in[13];
    const float* ut_cont_w   = (const float*)d_in[14];
    const float* ut_cont_b   = (const float*)d_in[15];
    const float* ut_w1       = (const float*)d_in[16];
    const float* ut_b1       = (const float*)d_in[17];
    const float* ut_g        = (const float*)d_in[18];
    const float* ut_be       = (const float*)d_in[19];
    const float* ut_w2       = (const float*)d_in[20];
    const float* ut_b2       = (const float*)d_in[21];
    const float* it_cont_w   = (const float*)d_in[22];
    const float* it_cont_b   = (const float*)d_in[23];
    const float* it_w1       = (const float*)d_in[24];
    const float* it_b1       = (const float*)d_in[25];
    const float* it_g        = (const float*)d_in[26];
    const float* it_be       = (const float*)d_in[27];
    const float* it_w2       = (const float*)d_in[28];
    const float* it_b2       = (const float*)d_in[29];

    const int B = in_sizes[0];          // 16384
    float* hist_pool = (float*)d_ws;    // [B,64] = 4MB

    hipLaunchKernelGGL(hist_pool_kernel, dim3(B / 4), dim3(256), 0, stream,
        history, ts_diff, emb_item, hist_pool, B);

    hipLaunchKernelGGL(user_tower_kernel, dim3(B / 64), dim3(256), 0, stream,
        user_id, top_genres, hist_pool, u_avg, activity,
        emb_genre, emb_user, ut_cont_w, ut_cont_b,
        ut_w1, ut_b1, ut_g, ut_be, ut_w2, ut_b2,
        (float*)d_out, B);

    hipLaunchKernelGGL(item_tower_kernel, dim3(B / 64), dim3(256), 0, stream,
        item_id, tmdb_genres, rel_year, i_avg, revenue,
        emb_item, emb_genre, it_cont_w, it_cont_b,
        it_w1, it_b1, it_g, it_be, it_w2, it_b2,
        (float*)d_out, B);
}

// Round 5
// 92.185 us; speedup vs baseline: 11.3543x; 1.6844x over previous
//
#include <hip/hip_runtime.h>

#define DD 64
#define LL 200
#define LP 256     // LL padded to multiple of 64
#define GG 6
#define LAMBDA 0.001f

typedef __attribute__((ext_vector_type(8))) short s8v;   // 8 bf16 (4 VGPRs)
typedef __attribute__((ext_vector_type(4))) float f4v;   // MFMA accumulator

__device__ __forceinline__ float wave_reduce_sum(float v) {
    #pragma unroll
    for (int off = 32; off > 0; off >>= 1)
        v += __shfl_xor(v, off, 64);
    return v;
}

__device__ __forceinline__ unsigned short f2bf(float f) {
    union { float f; unsigned int u; } v; v.f = f;
    return (unsigned short)((v.u + 0x7FFFu + ((v.u >> 16) & 1u)) >> 16);  // RNE
}

//======================================================================
// Kernel 0: convert emb_item fp32 -> bf16 table in workspace.
//======================================================================
__global__ __launch_bounds__(256)
void convert_kernel(const float* __restrict__ in, unsigned short* __restrict__ out, int n4)
{
    const int stride = gridDim.x * blockDim.x;
    for (int i = blockIdx.x * blockDim.x + threadIdx.x; i < n4; i += stride) {
        const float4 f = *(const float4*)&in[(size_t)i * 4];
        ushort4 o;
        o.x = f2bf(f.x); o.y = f2bf(f.y); o.z = f2bf(f.z); o.w = f2bf(f.w);
        *(ushort4*)&out[(size_t)i * 4] = o;
    }
}

//======================================================================
// Kernel 1: history pooling from bf16 table. One wave per row.
// 16-lane groups; each lane loads 8B (4 bf16) per entry; 16 in flight.
//======================================================================
__global__ __launch_bounds__(256)
void hist_pool_kernel(const int* __restrict__ history,
                      const float* __restrict__ ts_diff,
                      const unsigned short* __restrict__ emb_bf16,
                      float* __restrict__ hist_out, int B)
{
    const int wave = threadIdx.x >> 6;
    const int lane = threadIdx.x & 63;
    const int b = blockIdx.x * 4 + wave;
    const int g = lane >> 4;      // entry subgroup 0..3
    const int c = lane & 15;      // 4-dim chunk within row

    __shared__ float2 s_p[4][LP];

    const int*   hrow = history + (size_t)b * LL;
    const float* trow = ts_diff + (size_t)b * LL;

    float wpart = 0.f;
    #pragma unroll
    for (int l = lane; l < LP; l += 64) {
        int idx = 0; float w = 0.f;
        if (l < LL) {
            const int raw = hrow[l];
            if (raw > 0) { w = __expf(-LAMBDA * trow[l]); idx = raw; }
        }
        s_p[wave][l] = make_float2(w, __int_as_float(idx));
        wpart += w;
    }
    const float wsum = wave_reduce_sum(wpart);
    __syncthreads();

    float4 acc = make_float4(0.f, 0.f, 0.f, 0.f);
    #pragma unroll 1
    for (int l0 = 0; l0 < LP; l0 += 64) {
        uint2 e[16]; float w[16];
        #pragma unroll
        for (int i = 0; i < 16; ++i) {
            const float2 p = s_p[wave][l0 + i * 4 + g];
            w[i] = p.x;
            e[i] = *(const uint2*)&emb_bf16[(size_t)__float_as_int(p.y) * DD + c * 4];
        }
        #pragma unroll
        for (int i = 0; i < 16; ++i) {
            const float e0 = __uint_as_float(e[i].x << 16);
            const float e1 = __uint_as_float(e[i].x & 0xffff0000u);
            const float e2 = __uint_as_float(e[i].y << 16);
            const float e3 = __uint_as_float(e[i].y & 0xffff0000u);
            acc.x = fmaf(w[i], e0, acc.x);
            acc.y = fmaf(w[i], e1, acc.y);
            acc.z = fmaf(w[i], e2, acc.z);
            acc.w = fmaf(w[i], e3, acc.w);
        }
    }
    // reduce across the 4 entry-subgroups (lanes differing in bits 4,5)
    #pragma unroll
    for (int off = 16; off <= 32; off <<= 1) {
        acc.x += __shfl_xor(acc.x, off, 64);
        acc.y += __shfl_xor(acc.y, off, 64);
        acc.z += __shfl_xor(acc.z, off, 64);
        acc.w += __shfl_xor(acc.w, off, 64);
    }
    if (g == 0) {
        const float inv = 1.f / (wsum + 1e-8f);
        float4 o = make_float4(acc.x * inv, acc.y * inv, acc.z * inv, acc.w * inv);
        *(float4*)&hist_out[(size_t)b * DD + c * 4] = o;
    }
}

//======================================================================
// X/H fragment slot: A-operand layout for mfma_f32_16x16x32_bf16:
//   lane' = ((d>>3)&3)*16 + (r&15),  j = d&7,  k-step = d>>5
//======================================================================
#define PUT_FRAG(buf, NKS, r, d, val)                                   \
    do {                                                                \
        const int _mt = (r) >> 4, _ks = (d) >> 5;                       \
        const int _lp = (((d) >> 3) & 3) * 16 + ((r) & 15);             \
        (buf)[(((_mt) * (NKS) + _ks) * 64 + _lp) * 8 + ((d) & 7)] = f2bf(val); \
    } while (0)

//======================================================================
// Kernel 2: user tower (256 -> 128 -> 64), 64 rows/block, 8 waves.
//======================================================================
__global__ __launch_bounds__(512)
void user_tower_kernel(
    const int* __restrict__ user_id, const int* __restrict__ top_genres,
    const float* __restrict__ hist_pool,
    const float* __restrict__ u_avg, const float* __restrict__ activity,
    const float* __restrict__ emb_genre, const float* __restrict__ emb_user,
    const float* __restrict__ cont_w, const float* __restrict__ cont_b,
    const float* __restrict__ w1, const float* __restrict__ b1,
    const float* __restrict__ gam, const float* __restrict__ bet,
    const float* __restrict__ w2, const float* __restrict__ b2,
    float* __restrict__ out, int B)
{
    const int tid = threadIdx.x, wave = tid >> 6, lane = tid & 63;
    const int r0 = blockIdx.x * 64;

    __shared__ __align__(16) unsigned short sW1[8 * 8 * 64 * 8];  // 64KB frag-order
    __shared__ __align__(16) unsigned short sW2[4 * 4 * 64 * 8];  // 16KB frag-order
    __shared__ __align__(16) unsigned char  sC[64 * 128 * 4];     // 32KB: Xfrag -> y -> o
    __shared__ __align__(16) unsigned short sHf[4 * 4 * 64 * 8];  // 16KB h frag-order

    unsigned short* sXf = (unsigned short*)sC;
    float* sY = (float*)sC;
    float* sO = (float*)sC;

    //---- stage W1 [128][256] -> frag order (512 threads) ----
    {
        const int r = tid >> 2, q = tid & 3;
        #pragma unroll
        for (int c = 0; c < 8; ++c) {
            const int k = q * 64 + c * 8;
            const float4 f0 = *(const float4*)&w1[r * 256 + k];
            const float4 f1 = *(const float4*)&w1[r * 256 + k + 4];
            const int ks = k >> 5, lg = (k >> 3) & 3;
            const int lp = lg * 16 + (r & 15), nt = r >> 4;
            s8v wv;
            wv[0] = (short)f2bf(f0.x); wv[1] = (short)f2bf(f0.y);
            wv[2] = (short)f2bf(f0.z); wv[3] = (short)f2bf(f0.w);
            wv[4] = (short)f2bf(f1.x); wv[5] = (short)f2bf(f1.y);
            wv[6] = (short)f2bf(f1.z); wv[7] = (short)f2bf(f1.w);
            *(s8v*)&sW1[((ks * 8 + nt) * 64 + lp) * 8] = wv;
        }
    }
    //---- stage W2 [64][128] -> frag order ----
    {
        const int r = tid & 63, cb = (tid >> 6) * 2;
        #pragma unroll
        for (int c = cb; c < cb + 2; ++c) {
            const int k = c * 8;
            const float4 f0 = *(const float4*)&w2[r * 128 + k];
            const float4 f1 = *(const float4*)&w2[r * 128 + k + 4];
            const int ks = k >> 5, lg = (k >> 3) & 3;
            const int lp = lg * 16 + (r & 15), nt = r >> 4;
            s8v wv;
            wv[0] = (short)f2bf(f0.x); wv[1] = (short)f2bf(f0.y);
            wv[2] = (short)f2bf(f0.z); wv[3] = (short)f2bf(f0.w);
            wv[4] = (short)f2bf(f1.x); wv[5] = (short)f2bf(f1.y);
            wv[6] = (short)f2bf(f1.z); wv[7] = (short)f2bf(f1.w);
            *(s8v*)&sW2[((ks * 4 + nt) * 64 + lp) * 8] = wv;
        }
    }
    //---- build X features (wave -> rows wave*8..+7) ----
    #pragma unroll 2
    for (int i = 0; i < 8; ++i) {
        const int r = wave * 8 + i, b = r0 + r;
        const float ue = emb_user[(size_t)user_id[b] * DD + lane];
        const float hp = hist_pool[(size_t)b * DD + lane];
        const int* grow = top_genres + (size_t)b * GG;
        float gacc = 0.f, gw = 0.f;
        #pragma unroll
        for (int g = 0; g < GG; ++g) {
            const int idx = grow[g];
            const float m = (idx > 0) ? 1.f : 0.f;
            gacc = fmaf(m, emb_genre[idx * DD + lane], gacc);
            gw += m;
        }
        const float ug = gacc / (gw + 1e-8f);
        float uc = fmaf(u_avg[b], cont_w[lane * 2 + 0],
                   fmaf(activity[b], cont_w[lane * 2 + 1], cont_b[lane]));
        uc = fmaxf(uc, 0.f);
        PUT_FRAG(sXf, 8, r, lane, ue);
        PUT_FRAG(sXf, 8, r, 64 + lane, hp);
        PUT_FRAG(sXf, 8, r, 128 + lane, ug);
        PUT_FRAG(sXf, 8, r, 192 + lane, uc);
    }
    __syncthreads();

    //---- L1 MFMA: M=64, N=128, K=256. wave: mh=wave>>2, nh=wave&3 ----
    const int mh = wave >> 2, nh = wave & 3;
    f4v acc[2][2];
    const f4v zero4 = {0.f, 0.f, 0.f, 0.f};
    #pragma unroll
    for (int a = 0; a < 2; ++a)
        #pragma unroll
        for (int c = 0; c < 2; ++c) acc[a][c] = zero4;

    #pragma unroll
    for (int ks = 0; ks < 8; ++ks) {
        s8v av[2], bv[2];
        #pragma unroll
        for (int ml = 0; ml < 2; ++ml)
            av[ml] = *(const s8v*)&sXf[(((mh * 2 + ml) * 8 + ks) * 64 + lane) * 8];
        #pragma unroll
        for (int nl = 0; nl < 2; ++nl)
            bv[nl] = *(const s8v*)&sW1[((ks * 8 + nh * 2 + nl) * 64 + lane) * 8];
        #pragma unroll
        for (int ml = 0; ml < 2; ++ml)
            #pragma unroll
            for (int nl = 0; nl < 2; ++nl)
                acc[ml][nl] = __builtin_amdgcn_mfma_f32_16x16x32_bf16(av[ml], bv[nl], acc[ml][nl], 0, 0, 0);
    }
    __syncthreads();

    //---- y = acc + b1 -> sY [64][128] fp32 ----
    #pragma unroll
    for (int ml = 0; ml < 2; ++ml) {
        #pragma unroll
        for (int nl = 0; nl < 2; ++nl) {
            const int n = (nh * 2 + nl) * 16 + (lane & 15);
            const float bb = b1[n];
            #pragma unroll
            for (int rg = 0; rg < 4; ++rg) {
                const int m = (mh * 2 + ml) * 16 + (lane >> 4) * 4 + rg;
                sY[m * 128 + n] = acc[ml][nl][rg] + bb;
            }
        }
    }
    __syncthreads();

    //---- LN + ReLU -> sHf (rows wave*8..+7) ----
    {
        const float g0 = gam[lane], g1 = gam[lane + 64];
        const float e0 = bet[lane], e1 = bet[lane + 64];
        for (int i = 0; i < 8; ++i) {
            const int r = wave * 8 + i;
            const float a = sY[r * 128 + lane];
            const float c = sY[r * 128 + 64 + lane];
            const float mean = wave_reduce_sum(a + c) * (1.f / 128.f);
            const float da = a - mean, dc = c - mean;
            const float var = wave_reduce_sum(da * da + dc * dc) * (1.f / 128.f);
            const float rstd = rsqrtf(var + 1e-5f);
            const float h0 = fmaxf(fmaf(da * rstd, g0, e0), 0.f);
            const float h1 = fmaxf(fmaf(dc * rstd, g1, e1), 0.f);
            PUT_FRAG(sHf, 4, r, lane, h0);
            PUT_FRAG(sHf, 4, r, 64 + lane, h1);
        }
    }
    __syncthreads();

    //---- L2 MFMA: M=64, N=64, K=128. wave: 2 mtiles x 1 ntile ----
    f4v acc2[2];
    acc2[0] = zero4; acc2[1] = zero4;
    #pragma unroll
    for (int ks = 0; ks < 4; ++ks) {
        s8v av[2], bv;
        #pragma unroll
        for (int ml = 0; ml < 2; ++ml)
            av[ml] = *(const s8v*)&sHf[(((mh * 2 + ml) * 4 + ks) * 64 + lane) * 8];
        bv = *(const s8v*)&sW2[((ks * 4 + nh) * 64 + lane) * 8];
        #pragma unroll
        for (int ml = 0; ml < 2; ++ml)
            acc2[ml] = __builtin_amdgcn_mfma_f32_16x16x32_bf16(av[ml], bv, acc2[ml], 0, 0, 0);
    }
    #pragma unroll
    for (int ml = 0; ml < 2; ++ml) {
        const int n = nh * 16 + (lane & 15);
        const float bb = b2[n];
        #pragma unroll
        for (int rg = 0; rg < 4; ++rg) {
            const int m = (mh * 2 + ml) * 16 + (lane >> 4) * 4 + rg;
            sO[m * 64 + n] = acc2[ml][rg] + bb;
        }
    }
    __syncthreads();

    //---- l2norm + store (rows wave*8..+7) ----
    for (int i = 0; i < 8; ++i) {
        const int r = wave * 8 + i;
        const float o = sO[r * 64 + lane];
        const float nrm = sqrtf(wave_reduce_sum(o * o));
        out[(size_t)(r0 + r) * DD + lane] = o / fmaxf(nrm, 1e-12f);
    }
}

//======================================================================
// Kernel 3: item tower (192 -> 128 -> 64), 64 rows/block, 8 waves.
//======================================================================
__global__ __launch_bounds__(512)
void item_tower_kernel(
    const int* __restrict__ item_id, const int* __restrict__ tmdb_genres,
    const float* __restrict__ rel_year, const float* __restrict__ i_avg,
    const float* __restrict__ revenue,
    const float* __restrict__ emb_item, const float* __restrict__ emb_genre,
    const float* __restrict__ cont_w, const float* __restrict__ cont_b,
    const float* __restrict__ w1, const float* __restrict__ b1,
    const float* __restrict__ gam, const float* __restrict__ bet,
    const float* __restrict__ w2, const float* __restrict__ b2,
    float* __restrict__ out, int B)
{
    const int tid = threadIdx.x, wave = tid >> 6, lane = tid & 63;
    const int r0 = blockIdx.x * 64;

    __shared__ __align__(16) unsigned short sW1[6 * 8 * 64 * 8];  // 48KB
    __shared__ __align__(16) unsigned short sW2[4 * 4 * 64 * 8];  // 16KB
    __shared__ __align__(16) unsigned char  sC[64 * 128 * 4];     // 32KB
    __shared__ __align__(16) unsigned short sHf[4 * 4 * 64 * 8];  // 16KB

    unsigned short* sXf = (unsigned short*)sC;
    float* sY = (float*)sC;
    float* sO = (float*)sC;

    //---- stage W1 [128][192] -> frag order ----
    {
        const int r = tid >> 2, q = tid & 3;
        #pragma unroll
        for (int c = 0; c < 6; ++c) {
            const int k = q * 48 + c * 8;
            const float4 f0 = *(const float4*)&w1[r * 192 + k];
            const float4 f1 = *(const float4*)&w1[r * 192 + k + 4];
            const int ks = k >> 5, lg = (k >> 3) & 3;
            const int lp = lg * 16 + (r & 15), nt = r >> 4;
            s8v wv;
            wv[0] = (short)f2bf(f0.x); wv[1] = (short)f2bf(f0.y);
            wv[2] = (short)f2bf(f0.z); wv[3] = (short)f2bf(f0.w);
            wv[4] = (short)f2bf(f1.x); wv[5] = (short)f2bf(f1.y);
            wv[6] = (short)f2bf(f1.z); wv[7] = (short)f2bf(f1.w);
            *(s8v*)&sW1[((ks * 8 + nt) * 64 + lp) * 8] = wv;
        }
    }
    //---- stage W2 [64][128] -> frag order ----
    {
        const int r = tid & 63, cb = (tid >> 6) * 2;
        #pragma unroll
        for (int c = cb; c < cb + 2; ++c) {
            const int k = c * 8;
            const float4 f0 = *(const float4*)&w2[r * 128 + k];
            const float4 f1 = *(const float4*)&w2[r * 128 + k + 4];
            const int ks = k >> 5, lg = (k >> 3) & 3;
            const int lp = lg * 16 + (r & 15), nt = r >> 4;
            s8v wv;
            wv[0] = (short)f2bf(f0.x); wv[1] = (short)f2bf(f0.y);
            wv[2] = (short)f2bf(f0.z); wv[3] = (short)f2bf(f0.w);
            wv[4] = (short)f2bf(f1.x); wv[5] = (short)f2bf(f1.y);
            wv[6] = (short)f2bf(f1.z); wv[7] = (short)f2bf(f1.w);
            *(s8v*)&sW2[((ks * 4 + nt) * 64 + lp) * 8] = wv;
        }
    }
    //---- build X features ----
    #pragma unroll 2
    for (int i = 0; i < 8; ++i) {
        const int r = wave * 8 + i, b = r0 + r;
        const float ie = emb_item[(size_t)item_id[b] * DD + lane];
        const int* grow = tmdb_genres + (size_t)b * GG;
        float gacc = 0.f, gw = 0.f;
        #pragma unroll
        for (int g = 0; g < GG; ++g) {
            const int idx = grow[g];
            const float m = (idx > 0) ? 1.f : 0.f;
            gacc = fmaf(m, emb_genre[idx * DD + lane], gacc);
            gw += m;
        }
        const float ig = gacc / (gw + 1e-8f);
        float ic = fmaf(rel_year[b], cont_w[lane * 3 + 0],
                   fmaf(i_avg[b],   cont_w[lane * 3 + 1],
                   fmaf(revenue[b], cont_w[lane * 3 + 2], cont_b[lane])));
        ic = fmaxf(ic, 0.f);
        PUT_FRAG(sXf, 6, r, lane, ie);
        PUT_FRAG(sXf, 6, r, 64 + lane, ig);
        PUT_FRAG(sXf, 6, r, 128 + lane, ic);
    }
    __syncthreads();

    //---- L1 MFMA: M=64, N=128, K=192 ----
    const int mh = wave >> 2, nh = wave & 3;
    f4v acc[2][2];
    const f4v zero4 = {0.f, 0.f, 0.f, 0.f};
    #pragma unroll
    for (int a = 0; a < 2; ++a)
        #pragma unroll
        for (int c = 0; c < 2; ++c) acc[a][c] = zero4;

    #pragma unroll
    for (int ks = 0; ks < 6; ++ks) {
        s8v av[2], bv[2];
        #pragma unroll
        for (int ml = 0; ml < 2; ++ml)
            av[ml] = *(const s8v*)&sXf[(((mh * 2 + ml) * 6 + ks) * 64 + lane) * 8];
        #pragma unroll
        for (int nl = 0; nl < 2; ++nl)
            bv[nl] = *(const s8v*)&sW1[((ks * 8 + nh * 2 + nl) * 64 + lane) * 8];
        #pragma unroll
        for (int ml = 0; ml < 2; ++ml)
            #pragma unroll
            for (int nl = 0; nl < 2; ++nl)
                acc[ml][nl] = __builtin_amdgcn_mfma_f32_16x16x32_bf16(av[ml], bv[nl], acc[ml][nl], 0, 0, 0);
    }
    __syncthreads();

    #pragma unroll
    for (int ml = 0; ml < 2; ++ml) {
        #pragma unroll
        for (int nl = 0; nl < 2; ++nl) {
            const int n = (nh * 2 + nl) * 16 + (lane & 15);
            const float bb = b1[n];
            #pragma unroll
            for (int rg = 0; rg < 4; ++rg) {
                const int m = (mh * 2 + ml) * 16 + (lane >> 4) * 4 + rg;
                sY[m * 128 + n] = acc[ml][nl][rg] + bb;
            }
        }
    }
    __syncthreads();

    {
        const float g0 = gam[lane], g1 = gam[lane + 64];
        const float e0 = bet[lane], e1 = bet[lane + 64];
        for (int i = 0; i < 8; ++i) {
            const int r = wave * 8 + i;
            const float a = sY[r * 128 + lane];
            const float c = sY[r * 128 + 64 + lane];
            const float mean = wave_reduce_sum(a + c) * (1.f / 128.f);
            const float da = a - mean, dc = c - mean;
            const float var = wave_reduce_sum(da * da + dc * dc) * (1.f / 128.f);
            const float rstd = rsqrtf(var + 1e-5f);
            const float h0 = fmaxf(fmaf(da * rstd, g0, e0), 0.f);
            const float h1 = fmaxf(fmaf(dc * rstd, g1, e1), 0.f);
            PUT_FRAG(sHf, 4, r, lane, h0);
            PUT_FRAG(sHf, 4, r, 64 + lane, h1);
        }
    }
    __syncthreads();

    f4v acc2[2];
    acc2[0] = zero4; acc2[1] = zero4;
    #pragma unroll
    for (int ks = 0; ks < 4; ++ks) {
        s8v av[2], bv;
        #pragma unroll
        for (int ml = 0; ml < 2; ++ml)
            av[ml] = *(const s8v*)&sHf[(((mh * 2 + ml) * 4 + ks) * 64 + lane) * 8];
        bv = *(const s8v*)&sW2[((ks * 4 + nh) * 64 + lane) * 8];
        #pragma unroll
        for (int ml = 0; ml < 2; ++ml)
            acc2[ml] = __builtin_amdgcn_mfma_f32_16x16x32_bf16(av[ml], bv, acc2[ml], 0, 0, 0);
    }
    #pragma unroll
    for (int ml = 0; ml < 2; ++ml) {
        const int n = nh * 16 + (lane & 15);
        const float bb = b2[n];
        #pragma unroll
        for (int rg = 0; rg < 4; ++rg) {
            const int m = (mh * 2 + ml) * 16 + (lane >> 4) * 4 + rg;
            sO[m * 64 + n] = acc2[ml][rg] + bb;
        }
    }
    __syncthreads();

    for (int i = 0; i < 8; ++i) {
        const int r = wave * 8 + i;
        const float o = sO[r * 64 + lane];
        const float nrm = sqrtf(wave_reduce_sum(o * o));
        out[(size_t)B * DD + (size_t)(r0 + r) * DD + lane] = o / fmaxf(nrm, 1e-12f);
    }
}

extern "C" void kernel_launch(void* const* d_in, const int* in_sizes, int n_in,
                              void* d_out, int out_size, void* d_ws, size_t ws_size,
                              hipStream_t stream) {
    const int*   user_id     = (const int*)  d_in[0];
    const int*   history     = (const int*)  d_in[1];
    const int*   top_genres  = (const int*)  d_in[2];
    const int*   item_id     = (const int*)  d_in[3];
    const int*   tmdb_genres = (const int*)  d_in[4];
    const float* ts_diff     = (const float*)d_in[5];
    const float* u_avg       = (const float*)d_in[6];
    const float* activity    = (const float*)d_in[7];
    const float* rel_year    = (const float*)d_in[8];
    const float* i_avg       = (const float*)d_in[9];
    const float* revenue     = (const float*)d_in[10];
    const float* emb_item    = (const float*)d_in[11];
    const float* emb_genre   = (const float*)d_in[12];
    const float* emb_user    = (const float*)d_in[13];
    const float* ut_cont_w   = (const float*)d_in[14];
    const float* ut_cont_b   = (const float*)d_in[15];
    const float* ut_w1       = (const float*)d_in[16];
    const float* ut_b1       = (const float*)d_in[17];
    const float* ut_g        = (const float*)d_in[18];
    const float* ut_be       = (const float*)d_in[19];
    const float* ut_w2       = (const float*)d_in[20];
    const float* ut_b2       = (const float*)d_in[21];
    const float* it_cont_w   = (const float*)d_in[22];
    const float* it_cont_b   = (const float*)d_in[23];
    const float* it_w1       = (const float*)d_in[24];
    const float* it_b1       = (const float*)d_in[25];
    const float* it_g        = (const float*)d_in[26];
    const float* it_be       = (const float*)d_in[27];
    const float* it_w2       = (const float*)d_in[28];
    const float* it_b2       = (const float*)d_in[29];

    const int B = in_sizes[0];                 // 16384
    const int n_item = in_sizes[11];           // V_ITEM * 64

    float* hist_pool = (float*)d_ws;                                   // 4MB
    unsigned short* emb_bf16 = (unsigned short*)((char*)d_ws + (size_t)B * DD * sizeof(float));

    hipLaunchKernelGGL(convert_kernel, dim3(2048), dim3(256), 0, stream,
        emb_item, emb_bf16, n_item / 4);

    hipLaunchKernelGGL(hist_pool_kernel, dim3(B / 4), dim3(256), 0, stream,
        history, ts_diff, emb_bf16, hist_pool, B);

    hipLaunchKernelGGL(user_tower_kernel, dim3(B / 64), dim3(512), 0, stream,
        user_id, top_genres, hist_pool, u_avg, activity,
        emb_genre, emb_user, ut_cont_w, ut_cont_b,
        ut_w1, ut_b1, ut_g, ut_be, ut_w2, ut_b2,
        (float*)d_out, B);

    hipLaunchKernelGGL(item_tower_kernel, dim3(B / 64), dim3(512), 0, stream,
        item_id, tmdb_genres, rel_year, i_avg, revenue,
        emb_item, emb_genre, it_cont_w, it_cont_b,
        it_w1, it_b1, it_g, it_be, it_w2, it_b2,
        (float*)d_out, B);
}